// Round 21
// baseline (522.991 us; speedup 1.0000x reference)
//
#include <hip/hip_runtime.h>
#include <math.h>

#define B_ 16
#define T_TOT 16
#define C_ 1000
#define N_ 16000          // B_*C_
#define E_ 16000
#define HID 64
#define EMB 32
#define IN_DIM 16
#define XF 17             // dynamic x rows (xn, y, 15 feats); emb rows folded
#define HIST 8
#define SXP 160           // sxh row pitch: 17 dyn + 64 gcn + 15 pad + 64 hn = 160 = 5*32
#define HOFF 96           // hn rows 96..159 (K-steps 3,4); x-side rows 0..95 (K-steps 0..2)
#define SHP 168           // bf16 hi/lo row pitch (16B-aligned rows)
#define SGP 268           // gates / merge buffer pitch
#define Q_ 16             // scatter partitions

typedef __attribute__((ext_vector_type(8))) short bf16x8;
typedef __attribute__((ext_vector_type(4))) float f32x4;

__device__ __forceinline__ float sigmoidf_(float x) { return 1.f / (1.f + expf(-x)); }

// ---------------- init: zero hn, xn, cnt ----------------
__global__ void k_init(float* __restrict__ hn, float* __restrict__ xn, int* __restrict__ cnt) {
  int total = N_ * HID + N_ + C_;
  for (int i = blockIdx.x * 256 + threadIdx.x; i < total; i += gridDim.x * 256) {
    if (i < N_ * HID) hn[i] = 0.f;
    else if (i < N_ * HID + N_) xn[i - N_ * HID] = 0.f;
    else cnt[i - N_ * HID - N_] = 0;
  }
}

// ---------------- prep: B-fragment-ordered bf16 hi/lo GRU weights + WihT2 ----------------
__global__ void k_prep(const float* __restrict__ W_ih, const float* __restrict__ W_hh,
                       unsigned short* __restrict__ WBhi, unsigned short* __restrict__ WBlo,
                       float* __restrict__ WihT2) {
  int i = blockIdx.x * 256 + threadIdx.x;
  if (i < 30720) {
    const int j = i & 7;
    const int l = (i >> 3) & 63;
    const int ksnt = i >> 9;
    const int ks = ksnt % 5, nt = ksnt / 5;
    const int k = ks * 32 + (l >> 4) * 8 + j;
    const int g = nt * 16 + (l & 15);
    float w = 0.f;
    if (k < 17) w = W_ih[g * 113 + k];
    else if (k < 81) w = W_ih[g * 113 + 49 + (k - 17)];
    else if (k >= HOFF) w = W_hh[g * 64 + (k - HOFF)];
    const unsigned ub = __float_as_uint(w);
    const float hif = __uint_as_float(ub & 0xffff0000u);
    WBhi[i] = (unsigned short)(ub >> 16);
    WBlo[i] = (unsigned short)(__float_as_uint(w - hif) >> 16);
  } else if (i < 30720 + 32 * 192) {
    int i2 = i - 30720;
    int j2 = i2 / 192, g = i2 - j2 * 192;
    WihT2[i2] = W_ih[g * 113 + 17 + j2];
  }
}

// ---------------- embfold (once) ----------------
__global__ __launch_bounds__(256) void k_embfold(
    const float* __restrict__ emb_table,
    const float* __restrict__ Wq, const float* __restrict__ Wk,
    const float* __restrict__ Wv, const float* __restrict__ Wskip,
    const float* __restrict__ WihT2,
    float* __restrict__ embW, float* __restrict__ gihemb) {
  __shared__ float se[EMB];
  const int c = blockIdx.x;
  const int t = threadIdx.x;
  if (t < EMB) se[t] = emb_table[c * EMB + t];
  __syncthreads();
  const int mat = t >> 6, h = t & 63;
  const float* Wm = (mat == 0) ? Wq : (mat == 1) ? Wk : (mat == 2) ? Wv : Wskip;
  float acc = 0.f;
#pragma unroll
  for (int j = 0; j < EMB; ++j) acc = fmaf(se[j], Wm[(17 + j) * HID + h], acc);
  embW[c * 256 + t] = acc;
  if (t < 192) {
    float a2 = 0.f;
#pragma unroll
    for (int j = 0; j < EMB; ++j) a2 = fmaf(se[j], WihT2[j * 192 + t], a2);
    gihemb[c * 192 + t] = a2;
  }
}

// ---------------- CSR build ----------------
__global__ __launch_bounds__(256) void k_count(const int* __restrict__ dst,
                                               int* __restrict__ qcnt, int* __restrict__ cnt) {
  const int gw = (blockIdx.x * 256 + threadIdx.x) >> 6;
  const int lane = threadIdx.x & 63;
  const int d = gw >> 4, q = gw & (Q_ - 1);
  const int e0 = q * (E_ / Q_);
  int cur = 0;
  for (int base = 0; base < E_ / Q_; base += 64) {
    const bool in = (base + lane) < (E_ / Q_);
    const int e = e0 + (in ? base + lane : 0);
    cur += __popcll(__ballot(in && (dst[e] == d)));
  }
  if (lane == 0) { qcnt[(d << 4) + q] = cur; atomicAdd(&cnt[d], cur); }
}

__global__ __launch_bounds__(1024) void k_scan(const int* __restrict__ cnt, int* __restrict__ rowptr) {
  __shared__ int s[1024];
  int t = threadIdx.x;
  s[t] = (t < C_) ? cnt[t] : 0;
  __syncthreads();
  for (int off = 1; off < 1024; off <<= 1) {
    int v = (t >= off) ? s[t - off] : 0;
    __syncthreads();
    s[t] += v;
    __syncthreads();
  }
  if (t < C_) rowptr[t + 1] = s[t];
  if (t == 0) rowptr[0] = 0;
}

__global__ __launch_bounds__(256) void k_scatter(const int* __restrict__ dst,
                                                 const int* __restrict__ rowptr,
                                                 const int* __restrict__ qcnt,
                                                 int* __restrict__ csr_e) {
  const int gw = (blockIdx.x * 256 + threadIdx.x) >> 6;
  const int lane = threadIdx.x & 63;
  const int d = gw >> 4, q = gw & (Q_ - 1);
  int cur = rowptr[d];
  for (int qq = 0; qq < q; ++qq) cur += qcnt[(d << 4) + qq];
  const int e0 = q * (E_ / Q_);
  for (int base = 0; base < E_ / Q_; base += 64) {
    const bool in = (base + lane) < (E_ / Q_);
    const int e = e0 + (in ? base + lane : 0);
    const bool pred = in && (dst[e] == d);
    const unsigned long long mask = __ballot(pred);
    if (pred) csr_e[cur + __popcll(mask & ((1ull << lane) - 1))] = e;
    cur += __popcll(mask);
  }
}

// ---------------- pack: CSR-ordered per-(b,edge) record ----------------
__global__ __launch_bounds__(256) void k_pack(const int* __restrict__ src,
                                              const int* __restrict__ csr_e,
                                              const float* __restrict__ ea0,
                                              int4* __restrict__ pack) {
  const int idx = blockIdx.x * 256 + threadIdx.x;
  const int b = idx / E_, j = idx - b * E_;
  const int e = csr_e[j];
  const int se = src[b * 1000 + (e >> 4)];
  int4 rec;
  rec.x = b * C_ + src[e];
  rec.y = (e & 15) * C_ + se;
  rec.z = __float_as_int(ea0[2 * se]);
  rec.w = __float_as_int(ea0[2 * se + 1]);
  pack[idx] = rec;
}

// ---------------- per-node pre (t=0 only): k, v, wind ----------------
__global__ __launch_bounds__(256) void k_node_pre(
    const float* __restrict__ X, const float* __restrict__ y,
    const float* __restrict__ embW,
    const float* __restrict__ Wk, const float* __restrict__ bk,
    const float* __restrict__ Wv, const float* __restrict__ bv,
    const float* __restrict__ xn_prev,
    float* __restrict__ k, float* __restrict__ v, float2* __restrict__ wind, int t)
{
  __shared__ float sx[4][XF];
  const int local = threadIdx.x >> 6;
  const int h = threadIdx.x & 63;
  const int n = blockIdx.x * 4 + local;
  const int b = n / C_, c = n % C_;
  const float* Xrow = X + (((b * T_TOT + t) * C_ + c) * IN_DIM);

  if (h == 0)       sx[local][0] = xn_prev[n];
  else if (h == 1)  sx[local][1] = y[(b * T_TOT + t) * C_ + c];
  else if (h <= 16) sx[local][h] = Xrow[h - 2];
  if (h == 0) {
    float u10 = Xrow[13] * 3.0f + 0.5f;
    float v10 = Xrow[14] * 3.0f - 0.3f;
    float sp = hypotf(u10, v10);
    float dd = 1.5707963267948966f - atan2f(-v10, -u10);
    if (dd <= 0.f) dd += 6.283185307179586f;
    if (sp == 0.f) dd = 0.f;
    wind[n] = make_float2(sp, dd);
  }
  __syncthreads();

  const float* eW = embW + c * 256;
  float ak = bk[h] + eW[64 + h];
  float av = bv[h] + eW[128 + h];
#pragma unroll
  for (int j = 0; j < XF; ++j) {
    const float xv = sx[local][j];
    ak = fmaf(xv, Wk[j * HID + h], ak);
    av = fmaf(xv, Wv[j * HID + h], av);
  }
  k[(size_t)n * HID + h] = ak;
  v[(size_t)n * HID + h] = av;
}

// ---------------- fused main: 512 threads, 8 waves, 2 groups per node ----------------
// group parity par: A (waves 0-3) even 16-edge chunks, B (waves 4-7) odd chunks; states merged.
// GRU MFMA tiles split 12/8 waves; pointwise 2 nodes/wave; epilogue k(A) || v(B).
__global__ __launch_bounds__(512, 6) void k_node_main(
    const int* __restrict__ rowptr, const int4* __restrict__ pack,
    const float* __restrict__ X, const float* __restrict__ y,
    const float* __restrict__ xn_prev,
    const float* __restrict__ embW, const float* __restrict__ gihemb,
    const float* __restrict__ Wq, const float* __restrict__ bq,
    const float* __restrict__ Wskip, const float* __restrict__ bskip,
    const float* __restrict__ Wk, const float* __restrict__ bk,
    const float* __restrict__ Wv, const float* __restrict__ bv,
    const float* __restrict__ We, const float* __restrict__ be,
    const float* __restrict__ kR, const float* __restrict__ vR, const float2* __restrict__ windR,
    float* __restrict__ kW, float* __restrict__ vW, float2* __restrict__ windW,
    const unsigned short* __restrict__ WBhi, const unsigned short* __restrict__ WBlo,
    const float* __restrict__ b_ih, const float* __restrict__ b_hh,
    const float* __restrict__ Wout, const float* __restrict__ bout,
    const float* __restrict__ hn_in, float* __restrict__ hn_out, float* __restrict__ xn_out,
    int t, int last)
{
  __shared__ float sxh[16 * SXP];            // 10240 B
  __shared__ unsigned short sxhH[16 * SHP];  // 5376 B
  __shared__ unsigned short sxhL[16 * SHP];  // 5376 B
  __shared__ float sg[16 * SGP];             // 17152 B (attn-merge buffer, then gate preacts)

  const int h = threadIdx.x & 63;
  const int wv = threadIdx.x >> 6;          // 0..7
  const int par = wv >> 2;                  // 0 = A, 1 = B
  const int wq = wv & 3;
  const int grp = h >> 4, t16 = h & 15;
  const int gbase = h & 48;
  const int lb = ((int)blockIdx.x & 7) * 125 + ((int)blockIdx.x >> 3);
  const int nb0 = wq * 4;
  const int nloc = nb0 + grp;
  const int n = lb * 16 + nloc;
  const int b = n / C_, d = n % C_;

  const int r0 = rowptr[d];
  const int deg = rowptr[d + 1] - r0;
  const int4* packb = pack + (size_t)b * E_;

  // ---- build x rows 0..16 into sxh (A waves only) ----
  if (par == 0) {
#pragma unroll 1
    for (int i = 0; i < 4; ++i) {
      const int nl = nb0 + i;
      const int ng = lb * 16 + nl;
      const int bb = ng / C_, cc = ng % C_;
      const float* Xrow = X + (((size_t)(bb * T_TOT + t) * C_ + cc) * IN_DIM);
      float* row = &sxh[nl * SXP];
      if (h == 0)       row[0] = xn_prev[ng];
      else if (h == 1)  row[1] = y[(size_t)(bb * T_TOT + t) * C_ + cc];
      else if (h <= 16) row[h] = Xrow[h - 2];
    }
  }
  __syncthreads();

  // ---- own-node q/skip (16-lane float4 GEMV, both groups) + qproj butterflies ----
  float4 qv4, sk4, pA, pB;
  {
    const float* eW = embW + d * 256;
    {
      const float4 bq4 = *(const float4*)(bq + t16 * 4);
      const float4 eq4 = *(const float4*)(eW + t16 * 4);
      qv4 = make_float4(bq4.x + eq4.x, bq4.y + eq4.y, bq4.z + eq4.z, bq4.w + eq4.w);
      const float4 bs4 = *(const float4*)(bskip + t16 * 4);
      const float4 es4 = *(const float4*)(eW + 192 + t16 * 4);
      sk4 = make_float4(bs4.x + es4.x, bs4.y + es4.y, bs4.z + es4.z, bs4.w + es4.w);
    }
    const float* row = &sxh[nloc * SXP];
#pragma unroll 4
    for (int j = 0; j < XF; ++j) {
      const float xv = row[j];
      const float4 wq4 = *(const float4*)(Wq + j * HID + t16 * 4);
      const float4 ws = *(const float4*)(Wskip + j * HID + t16 * 4);
      qv4.x = fmaf(xv, wq4.x, qv4.x); qv4.y = fmaf(xv, wq4.y, qv4.y);
      qv4.z = fmaf(xv, wq4.z, qv4.z); qv4.w = fmaf(xv, wq4.w, qv4.w);
      sk4.x = fmaf(xv, ws.x, sk4.x); sk4.y = fmaf(xv, ws.y, sk4.y);
      sk4.z = fmaf(xv, ws.z, sk4.z); sk4.w = fmaf(xv, ws.w, sk4.w);
    }
    const float4 bee = *(const float4*)(be + t16 * 4);
    const float4 w0 = *(const float4*)(We + t16 * 4);
    const float4 w1 = *(const float4*)(We + 64 + t16 * 4);
    const float4 w2 = *(const float4*)(We + 128 + t16 * 4);
    const float4 w3 = *(const float4*)(We + 192 + t16 * 4);
    const float4 w4 = *(const float4*)(We + 256 + t16 * 4);
    float p0 = qv4.x * bee.x + qv4.y * bee.y + qv4.z * bee.z + qv4.w * bee.w;
    float p1 = qv4.x * w0.x + qv4.y * w0.y + qv4.z * w0.z + qv4.w * w0.w;
    float p2 = qv4.x * w1.x + qv4.y * w1.y + qv4.z * w1.z + qv4.w * w1.w;
    float p3 = qv4.x * w2.x + qv4.y * w2.y + qv4.z * w2.z + qv4.w * w2.w;
    float p4 = qv4.x * w3.x + qv4.y * w3.y + qv4.z * w3.z + qv4.w * w3.w;
    float p5 = qv4.x * w4.x + qv4.y * w4.y + qv4.z * w4.z + qv4.w * w4.w;
#pragma unroll
    for (int off = 1; off < 16; off <<= 1) {
      p0 += __shfl_xor(p0, off); p1 += __shfl_xor(p1, off); p2 += __shfl_xor(p2, off);
      p3 += __shfl_xor(p3, off); p4 += __shfl_xor(p4, off); p5 += __shfl_xor(p5, off);
    }
    pA = make_float4(p0, p1, p2, p3);
    pB = make_float4(p4, p5, 0.f, 0.f);
  }

  // ---- attention: A takes chunks 0,32,..; B takes 16,48,.. ----
  float m = -INFINITY, s = 0.f, S1 = 0.f, S2 = 0.f, S3 = 0.f, S4 = 0.f, S5 = 0.f;
  float4 o4 = make_float4(0.f, 0.f, 0.f, 0.f);

  for (int cb = par * 16; cb < deg; cb += 32) {
    const int nb = min(16, deg - cb);
    const int4 rec = packb[r0 + cb + (t16 < nb ? t16 : 0)];
    const int nsrc = rec.x;
    const float dist = __int_as_float(rec.z), dirc = __int_as_float(rec.w);
    const float2 w2w = windR[rec.y];
    const float sp = w2w.x, wd = w2w.y;
    const float adv = fmaxf(0.f, 3.f * sp * cosf(fabsf(dirc - wd)) / dist);
    float asc = pA.x;
    asc = fmaf(dist, pA.y, asc); asc = fmaf(dirc, pA.z, asc); asc = fmaf(sp, pA.w, asc);
    asc = fmaf(wd, pB.x, asc);   asc = fmaf(adv, pB.y, asc);

    float alpha = -INFINITY;
#pragma unroll 4
    for (int j = 0; j < nb; ++j) {
      const int sl = gbase | j;
      const int nsb = __shfl(nsrc, sl);
      const float4 kv = *(const float4*)(kR + (size_t)nsb * HID + t16 * 4);
      float part = qv4.x * kv.x + qv4.y * kv.y + qv4.z * kv.z + qv4.w * kv.w;
      part += __shfl_xor(part, 1);
      part += __shfl_xor(part, 2);
      part += __shfl_xor(part, 4);
      part += __shfl_xor(part, 8);
      const float af = (part + __shfl(asc, sl)) * 0.125f;   // 1/sqrt(64)
      if (t16 == j) alpha = af;
    }

    float mx = alpha;
    mx = fmaxf(mx, __shfl_xor(mx, 1));
    mx = fmaxf(mx, __shfl_xor(mx, 2));
    mx = fmaxf(mx, __shfl_xor(mx, 4));
    mx = fmaxf(mx, __shfl_xor(mx, 8));
    const float mnew = fmaxf(m, mx);
    const float scale = expf(m - mnew);
    const float a = expf(alpha - mnew);
    float ra = a, q1 = a * dist, q2 = a * dirc, q3 = a * sp, q4 = a * wd, q5 = a * adv;
#pragma unroll
    for (int off = 1; off < 16; off <<= 1) {
      ra += __shfl_xor(ra, off); q1 += __shfl_xor(q1, off); q2 += __shfl_xor(q2, off);
      q3 += __shfl_xor(q3, off); q4 += __shfl_xor(q4, off); q5 += __shfl_xor(q5, off);
    }
    s  = s * scale + ra;  S1 = S1 * scale + q1; S2 = S2 * scale + q2;
    S3 = S3 * scale + q3; S4 = S4 * scale + q4; S5 = S5 * scale + q5;
    o4.x *= scale; o4.y *= scale; o4.z *= scale; o4.w *= scale;
    m = mnew;

#pragma unroll 4
    for (int j = 0; j < nb; ++j) {
      const int sl = gbase | j;
      const float aj = __shfl(a, sl);
      const int nsb = __shfl(nsrc, sl);
      const float4 v4 = *(const float4*)(vR + (size_t)nsb * HID + t16 * 4);
      o4.x = fmaf(aj, v4.x, o4.x); o4.y = fmaf(aj, v4.y, o4.y);
      o4.z = fmaf(aj, v4.z, o4.z); o4.w = fmaf(aj, v4.w, o4.w);
    }
  }

  // ---- B publishes its state ----
  if (par == 1) {
    float* mg = &sg[nloc * SGP];
    mg[t16 * 4 + 0] = o4.x; mg[t16 * 4 + 1] = o4.y;
    mg[t16 * 4 + 2] = o4.z; mg[t16 * 4 + 3] = o4.w;
    if (t16 == 0) {
      mg[64] = m; mg[65] = s; mg[66] = S1; mg[67] = S2;
      mg[68] = S3; mg[69] = S4; mg[70] = S5;
    }
  }
  __syncthreads();

  // ---- A merges + reconstructs ----
  if (par == 0) {
    const float* mg = &sg[nloc * SGP];
    const float mB = mg[64], sB = mg[65];
    const float mM = fmaxf(m, mB);
    const float eA = (s  > 0.f) ? expf(m  - mM) : 0.f;
    const float eB = (sB > 0.f) ? expf(mB - mM) : 0.f;
    const float4 oB = *(const float4*)(mg + t16 * 4);
    s  = s * eA + sB * eB;
    S1 = S1 * eA + mg[66] * eB; S2 = S2 * eA + mg[67] * eB;
    S3 = S3 * eA + mg[68] * eB; S4 = S4 * eA + mg[69] * eB;
    S5 = S5 * eA + mg[70] * eB;
    o4.x = o4.x * eA + oB.x * eB; o4.y = o4.y * eA + oB.y * eB;
    o4.z = o4.z * eA + oB.z * eB; o4.w = o4.w * eA + oB.w * eB;

    const float4 be4 = *(const float4*)(be + t16 * 4);
    const float4 e0 = *(const float4*)(We + t16 * 4);
    const float4 e1 = *(const float4*)(We + 64 + t16 * 4);
    const float4 e2 = *(const float4*)(We + 128 + t16 * 4);
    const float4 e3 = *(const float4*)(We + 192 + t16 * 4);
    const float4 e4 = *(const float4*)(We + 256 + t16 * 4);
    const float inv = (s > 0.f) ? 1.f / s : 0.f;
    float* xr = &sxh[nloc * SXP];
    float ox, oy, oz, ow;
    ox = s * be4.x; ox = fmaf(S1, e0.x, ox); ox = fmaf(S2, e1.x, ox); ox = fmaf(S3, e2.x, ox); ox = fmaf(S4, e3.x, ox); ox = fmaf(S5, e4.x, ox);
    oy = s * be4.y; oy = fmaf(S1, e0.y, oy); oy = fmaf(S2, e1.y, oy); oy = fmaf(S3, e2.y, oy); oy = fmaf(S4, e3.y, oy); oy = fmaf(S5, e4.y, oy);
    oz = s * be4.z; oz = fmaf(S1, e0.z, oz); oz = fmaf(S2, e1.z, oz); oz = fmaf(S3, e2.z, oz); oz = fmaf(S4, e3.z, oz); oz = fmaf(S5, e4.z, oz);
    ow = s * be4.w; ow = fmaf(S1, e0.w, ow); ow = fmaf(S2, e1.w, ow); ow = fmaf(S3, e2.w, ow); ow = fmaf(S4, e3.w, ow); ow = fmaf(S5, e4.w, ow);
    xr[17 + t16 * 4 + 0] = sigmoidf_(sk4.x + (o4.x + ox) * inv);
    xr[17 + t16 * 4 + 1] = sigmoidf_(sk4.y + (o4.y + oy) * inv);
    xr[17 + t16 * 4 + 2] = sigmoidf_(sk4.z + (o4.z + oz) * inv);
    xr[17 + t16 * 4 + 3] = sigmoidf_(sk4.w + (o4.w + ow) * inv);
    const float4 hv4 = *(const float4*)(hn_in + (size_t)n * HID + t16 * 4);
    *(float4*)(&xr[HOFF + t16 * 4]) = hv4;
    if (t16 < 15) xr[81 + t16] = 0.f;
  }
  __syncthreads();

  // ---- convert sxh -> bf16 hi/lo (512 threads) ----
  for (int idx = threadIdx.x; idx < 16 * SXP; idx += 512) {
    const int nd = idx / SXP, rw = idx - nd * SXP;
    const float xv = sxh[idx];
    const unsigned ub = __float_as_uint(xv);
    const float hif = __uint_as_float(ub & 0xffff0000u);
    sxhH[nd * SHP + rw] = (unsigned short)(ub >> 16);
    sxhL[nd * SHP + rw] = (unsigned short)(__float_as_uint(xv - hif) >> 16);
  }
  __syncthreads();

  // ---- MFMA GRU: 12 n-tiles over 8 waves ----
  {
    const int lane = h;
    const int aoff = t16 * SHP + grp * 8;
#pragma unroll 1
    for (int nt = wv; nt < 12; nt += 8) {
      const unsigned short* bhp = WBhi + ((size_t)(nt * 5) * 64 + lane) * 8;
      const unsigned short* blp = WBlo + ((size_t)(nt * 5) * 64 + lane) * 8;
      const int nbase = grp * 4;
      if (nt < 8) {
        f32x4 acc = {0.f, 0.f, 0.f, 0.f};
#pragma unroll 1
        for (int ks = 0; ks < 5; ++ks) {
          const bf16x8 Ah = *(const bf16x8*)(&sxhH[aoff + ks * 32]);
          const bf16x8 Al = *(const bf16x8*)(&sxhL[aoff + ks * 32]);
          const bf16x8 Bh = *(const bf16x8*)(bhp + (size_t)ks * 512);
          const bf16x8 Bl = *(const bf16x8*)(blp + (size_t)ks * 512);
          acc = __builtin_amdgcn_mfma_f32_16x16x32_bf16(Ah, Bh, acc, 0, 0, 0);
          acc = __builtin_amdgcn_mfma_f32_16x16x32_bf16(Ah, Bl, acc, 0, 0, 0);
          acc = __builtin_amdgcn_mfma_f32_16x16x32_bf16(Al, Bh, acc, 0, 0, 0);
        }
        const int gc = nt * 16 + t16;
#pragma unroll
        for (int r = 0; r < 4; ++r) sg[(nbase + r) * SGP + gc] = acc[r];
      } else {
        f32x4 accX = {0.f, 0.f, 0.f, 0.f};
        f32x4 accH = {0.f, 0.f, 0.f, 0.f};
#pragma unroll 1
        for (int ks = 0; ks < 3; ++ks) {
          const bf16x8 Ah = *(const bf16x8*)(&sxhH[aoff + ks * 32]);
          const bf16x8 Al = *(const bf16x8*)(&sxhL[aoff + ks * 32]);
          const bf16x8 Bh = *(const bf16x8*)(bhp + (size_t)ks * 512);
          const bf16x8 Bl = *(const bf16x8*)(blp + (size_t)ks * 512);
          accX = __builtin_amdgcn_mfma_f32_16x16x32_bf16(Ah, Bh, accX, 0, 0, 0);
          accX = __builtin_amdgcn_mfma_f32_16x16x32_bf16(Ah, Bl, accX, 0, 0, 0);
          accX = __builtin_amdgcn_mfma_f32_16x16x32_bf16(Al, Bh, accX, 0, 0, 0);
        }
#pragma unroll 1
        for (int ks = 3; ks < 5; ++ks) {
          const bf16x8 Ah = *(const bf16x8*)(&sxhH[aoff + ks * 32]);
          const bf16x8 Al = *(const bf16x8*)(&sxhL[aoff + ks * 32]);
          const bf16x8 Bh = *(const bf16x8*)(bhp + (size_t)ks * 512);
          const bf16x8 Bl = *(const bf16x8*)(blp + (size_t)ks * 512);
          accH = __builtin_amdgcn_mfma_f32_16x16x32_bf16(Ah, Bh, accH, 0, 0, 0);
          accH = __builtin_amdgcn_mfma_f32_16x16x32_bf16(Ah, Bl, accH, 0, 0, 0);
          accH = __builtin_amdgcn_mfma_f32_16x16x32_bf16(Al, Bh, accH, 0, 0, 0);
        }
        const int gx = 128 + (nt - 8) * 16 + t16;
#pragma unroll
        for (int r = 0; r < 4; ++r) {
          sg[(nbase + r) * SGP + gx] = accX[r];
          sg[(nbase + r) * SGP + gx + 64] = accH[r];
        }
      }
    }
  }
  __syncthreads();

  // ---- pointwise GRU + output head: wave handles 2 nodes ----
  const float wo = Wout[h];
  const float bout0 = bout[0];
  const float bi0 = b_ih[h] + b_hh[h];
  const float bi1 = b_ih[64 + h] + b_hh[64 + h];
  const float bx = b_ih[128 + h], bh2 = b_hh[128 + h];
#pragma unroll 1
  for (int i = 0; i < 2; ++i) {
    const int nl = wv * 2 + i;
    const int ng = lb * 16 + nl;
    const int ci = ng % C_;
    const float* ge = gihemb + (size_t)ci * 192;
    const float rg = sigmoidf_(sg[nl * SGP + h] + bi0 + ge[h]);
    const float zg = sigmoidf_(sg[nl * SGP + 64 + h] + bi1 + ge[64 + h]);
    const float gxv = sg[nl * SGP + 128 + h] + bx + ge[128 + h];
    const float ghv = sg[nl * SGP + 192 + h] + bh2;
    const float hv = sxh[nl * SXP + HOFF + h];
    const float nn2 = tanhf(fmaf(rg, ghv, gxv));
    const float hnew = (1.f - zg) * nn2 + zg * hv;
    hn_out[(size_t)ng * HID + h] = hnew;
    float prod = hnew * wo;
#pragma unroll
    for (int off = 1; off < 64; off <<= 1) prod += __shfl_xor(prod, off);
    if (h == 0) {
      const float xnv = prod + bout0;
      xn_out[ng] = xnv;
      sxh[nl * SXP + 0] = xnv;          // LDS row 0 for this dispatch's epilogue
    }
  }

  // ---- epilogue (not last step): k(A) || v(B) for t+1 into alternate buffers ----
  if (!last) {
    const int t1 = t + 1;
    if (par == 0) {
#pragma unroll 1
      for (int i = 0; i < 4; ++i) {
        const int nl = nb0 + i;
        const int ng = lb * 16 + nl;
        const int bb = ng / C_, cc = ng % C_;
        const float* Xrow = X + (((size_t)(bb * T_TOT + t1) * C_ + cc) * IN_DIM);
        float* row = &sxh[nl * SXP];
        if (h == 1)                 row[1] = y[(size_t)(bb * T_TOT + t1) * C_ + cc];
        else if (h >= 2 && h <= 16) row[h] = Xrow[h - 2];
        if (h == 0) {
          float u10 = Xrow[13] * 3.0f + 0.5f;
          float v10 = Xrow[14] * 3.0f - 0.3f;
          float sp = hypotf(u10, v10);
          float dd = 1.5707963267948966f - atan2f(-v10, -u10);
          if (dd <= 0.f) dd += 6.283185307179586f;
          if (sp == 0.f) dd = 0.f;
          windW[ng] = make_float2(sp, dd);
        }
      }
    }
    __syncthreads();
    {
      const float* eW = embW + d * 256;
      const float* row = &sxh[nloc * SXP];
      if (par == 0) {
        float4 kk4;
        const float4 bk4 = *(const float4*)(bk + t16 * 4);
        const float4 ek4 = *(const float4*)(eW + 64 + t16 * 4);
        kk4 = make_float4(bk4.x + ek4.x, bk4.y + ek4.y, bk4.z + ek4.z, bk4.w + ek4.w);
#pragma unroll 1
        for (int j = 0; j < XF; ++j) {
          const float xv = row[j];
          const float4 wk = *(const float4*)(Wk + j * HID + t16 * 4);
          kk4.x = fmaf(xv, wk.x, kk4.x); kk4.y = fmaf(xv, wk.y, kk4.y);
          kk4.z = fmaf(xv, wk.z, kk4.z); kk4.w = fmaf(xv, wk.w, kk4.w);
        }
        *(float4*)(kW + (size_t)n * HID + t16 * 4) = kk4;
      } else {
        float4 vv4;
        const float4 bv4 = *(const float4*)(bv + t16 * 4);
        const float4 ev4 = *(const float4*)(eW + 128 + t16 * 4);
        vv4 = make_float4(bv4.x + ev4.x, bv4.y + ev4.y, bv4.z + ev4.z, bv4.w + ev4.w);
#pragma unroll 1
        for (int j = 0; j < XF; ++j) {
          const float xv = row[j];
          const float4 wvv = *(const float4*)(Wv + j * HID + t16 * 4);
          vv4.x = fmaf(xv, wvv.x, vv4.x); vv4.y = fmaf(xv, wvv.y, vv4.y);
          vv4.z = fmaf(xv, wvv.z, vv4.z); vv4.w = fmaf(xv, wvv.w, vv4.w);
        }
        *(float4*)(vW + (size_t)n * HID + t16 * 4) = vv4;
      }
    }
  }
}

extern "C" void kernel_launch(void* const* d_in, const int* in_sizes, int n_in,
                              void* d_out, int out_size, void* d_ws, size_t ws_size,
                              hipStream_t stream) {
  const float* X      = (const float*)d_in[0];
  const float* y      = (const float*)d_in[1];
  const float* ea0    = (const float*)d_in[2];
  const float* emb    = (const float*)d_in[3];
  const float* Wq     = (const float*)d_in[4];
  const float* bq     = (const float*)d_in[5];
  const float* Wk     = (const float*)d_in[6];
  const float* bk     = (const float*)d_in[7];
  const float* Wv     = (const float*)d_in[8];
  const float* bv     = (const float*)d_in[9];
  const float* We     = (const float*)d_in[10];
  const float* be     = (const float*)d_in[11];
  const float* Wskip  = (const float*)d_in[12];
  const float* bskip  = (const float*)d_in[13];
  const float* W_ih   = (const float*)d_in[14];
  const float* b_ih   = (const float*)d_in[15];
  const float* W_hh   = (const float*)d_in[16];
  const float* b_hh   = (const float*)d_in[17];
  const float* Wout   = (const float*)d_in[18];
  const float* bout   = (const float*)d_in[19];
  const int*   eidx   = (const int*)d_in[20];
  const int* src = eidx;
  const int* dst = eidx + E_;

  float* W = (float*)d_ws;
  size_t off = 0;
  float* kA    = W + off; off += (size_t)N_ * HID;
  float* kB    = W + off; off += (size_t)N_ * HID;
  float* vA    = W + off; off += (size_t)N_ * HID;
  float* vB    = W + off; off += (size_t)N_ * HID;
  float2* wiA  = (float2*)(W + off); off += (size_t)N_ * 2;
  float2* wiB  = (float2*)(W + off); off += (size_t)N_ * 2;
  float* hnA   = W + off; off += (size_t)N_ * HID;
  float* xnA   = W + off; off += N_;
  unsigned short* WBhi = (unsigned short*)(W + off); off += 30720 / 2;
  unsigned short* WBlo = (unsigned short*)(W + off); off += 30720 / 2;
  float* WihT2 = W + off; off += 32 * 192;
  float* embW  = W + off; off += (size_t)C_ * 256;
  float* gihemb= W + off; off += (size_t)C_ * 192;
  off = (off + 3) & ~(size_t)3;      // 16B-align pack
  int4* pack   = (int4*)(W + off); off += (size_t)B_ * E_ * 4;
  int* cnt     = (int*)(W + off); off += C_;
  int* rowptr  = (int*)(W + off); off += C_ + 1;
  int* qcnt    = (int*)(W + off); off += C_ * Q_;
  int* csr_e   = (int*)(W + off); off += E_;

  k_init<<<1024, 256, 0, stream>>>(hnA, xnA, cnt);
  k_prep<<<(30720 + 32 * 192 + 255) / 256, 256, 0, stream>>>(W_ih, W_hh, WBhi, WBlo, WihT2);
  k_embfold<<<C_, 256, 0, stream>>>(emb, Wq, Wk, Wv, Wskip, WihT2, embW, gihemb);
  k_count<<<C_ * Q_ / 4, 256, 0, stream>>>(dst, qcnt, cnt);
  k_scan<<<1, 1024, 0, stream>>>(cnt, rowptr);
  k_scatter<<<C_ * Q_ / 4, 256, 0, stream>>>(dst, rowptr, qcnt, csr_e);
  k_pack<<<B_ * E_ / 256, 256, 0, stream>>>(src, csr_e, ea0, pack);

  float* hn_final = (float*)d_out;
  float* xn_final = (float*)d_out + (size_t)N_ * HID;

  // t=0 producer
  k_node_pre<<<N_ / 4, 256, 0, stream>>>(X, y, embW, Wk, bk, Wv, bv,
                                         xnA, kA, vA, wiA, 0);

  for (int t = 0; t < HIST; ++t) {
    const bool last = (t == HIST - 1);
    const bool even = ((t & 1) == 0);
    k_node_main<<<N_ / 16, 512, 0, stream>>>(rowptr, pack, X, y, xnA, embW, gihemb,
                                             Wq, bq, Wskip, bskip, Wk, bk, Wv, bv, We, be,
                                             even ? kA : kB, even ? vA : vB, even ? wiA : wiB,
                                             even ? kB : kA, even ? vB : vA, even ? wiB : wiA,
                                             WBhi, WBlo,
                                             b_ih, b_hh, Wout, bout,
                                             hnA,
                                             last ? hn_final : hnA,
                                             last ? xn_final : xnA,
                                             t, last ? 1 : 0);
  }
}

// Round 22
// 395.650 us; speedup vs baseline: 1.3219x; 1.3219x over previous
//
#include <hip/hip_runtime.h>
#include <math.h>

#define B_ 16
#define T_TOT 16
#define C_ 1000
#define N_ 16000          // B_*C_
#define E_ 16000
#define HID 64
#define EMB 32
#define IN_DIM 16
#define XF 17             // dynamic x rows (xn, y, 15 feats); emb rows folded
#define HIST 8
#define SXP 160           // sxh row pitch: 17 dyn + 64 gcn + 15 pad + 64 hn = 160 = 5*32
#define HOFF 96           // hn rows 96..159 (K-steps 3,4); x-side rows 0..95 (K-steps 0..2)
#define SHP 168           // bf16 hi/lo row pitch (16B-aligned rows)
#define SGP 268           // gates buffer pitch
#define Q_ 16             // scatter partitions

typedef __attribute__((ext_vector_type(8))) short bf16x8;
typedef __attribute__((ext_vector_type(4))) float f32x4;

__device__ __forceinline__ float sigmoidf_(float x) { return 1.f / (1.f + expf(-x)); }

// ---------------- init: zero hn, xn, cnt ----------------
__global__ void k_init(float* __restrict__ hn, float* __restrict__ xn, int* __restrict__ cnt) {
  int total = N_ * HID + N_ + C_;
  for (int i = blockIdx.x * 256 + threadIdx.x; i < total; i += gridDim.x * 256) {
    if (i < N_ * HID) hn[i] = 0.f;
    else if (i < N_ * HID + N_) xn[i - N_ * HID] = 0.f;
    else cnt[i - N_ * HID - N_] = 0;
  }
}

// ---------------- prep: B-fragment-ordered bf16 hi/lo GRU weights + WihT2 ----------------
__global__ void k_prep(const float* __restrict__ W_ih, const float* __restrict__ W_hh,
                       unsigned short* __restrict__ WBhi, unsigned short* __restrict__ WBlo,
                       float* __restrict__ WihT2) {
  int i = blockIdx.x * 256 + threadIdx.x;
  if (i < 30720) {
    const int j = i & 7;
    const int l = (i >> 3) & 63;
    const int ksnt = i >> 9;
    const int ks = ksnt % 5, nt = ksnt / 5;
    const int k = ks * 32 + (l >> 4) * 8 + j;
    const int g = nt * 16 + (l & 15);
    float w = 0.f;
    if (k < 17) w = W_ih[g * 113 + k];
    else if (k < 81) w = W_ih[g * 113 + 49 + (k - 17)];
    else if (k >= HOFF) w = W_hh[g * 64 + (k - HOFF)];
    const unsigned ub = __float_as_uint(w);
    const float hif = __uint_as_float(ub & 0xffff0000u);
    WBhi[i] = (unsigned short)(ub >> 16);
    WBlo[i] = (unsigned short)(__float_as_uint(w - hif) >> 16);
  } else if (i < 30720 + 32 * 192) {
    int i2 = i - 30720;
    int j2 = i2 / 192, g = i2 - j2 * 192;
    WihT2[i2] = W_ih[g * 113 + 17 + j2];
  }
}

// ---------------- embfold (once) ----------------
__global__ __launch_bounds__(256) void k_embfold(
    const float* __restrict__ emb_table,
    const float* __restrict__ Wq, const float* __restrict__ Wk,
    const float* __restrict__ Wv, const float* __restrict__ Wskip,
    const float* __restrict__ WihT2,
    float* __restrict__ embW, float* __restrict__ gihemb) {
  __shared__ float se[EMB];
  const int c = blockIdx.x;
  const int t = threadIdx.x;
  if (t < EMB) se[t] = emb_table[c * EMB + t];
  __syncthreads();
  const int mat = t >> 6, h = t & 63;
  const float* Wm = (mat == 0) ? Wq : (mat == 1) ? Wk : (mat == 2) ? Wv : Wskip;
  float acc = 0.f;
#pragma unroll
  for (int j = 0; j < EMB; ++j) acc = fmaf(se[j], Wm[(17 + j) * HID + h], acc);
  embW[c * 256 + t] = acc;
  if (t < 192) {
    float a2 = 0.f;
#pragma unroll
    for (int j = 0; j < EMB; ++j) a2 = fmaf(se[j], WihT2[j * 192 + t], a2);
    gihemb[c * 192 + t] = a2;
  }
}

// ---------------- CSR build ----------------
__global__ __launch_bounds__(256) void k_count(const int* __restrict__ dst,
                                               int* __restrict__ qcnt, int* __restrict__ cnt) {
  const int gw = (blockIdx.x * 256 + threadIdx.x) >> 6;
  const int lane = threadIdx.x & 63;
  const int d = gw >> 4, q = gw & (Q_ - 1);
  const int e0 = q * (E_ / Q_);
  int cur = 0;
  for (int base = 0; base < E_ / Q_; base += 64) {
    const bool in = (base + lane) < (E_ / Q_);
    const int e = e0 + (in ? base + lane : 0);
    cur += __popcll(__ballot(in && (dst[e] == d)));
  }
  if (lane == 0) { qcnt[(d << 4) + q] = cur; atomicAdd(&cnt[d], cur); }
}

__global__ __launch_bounds__(1024) void k_scan(const int* __restrict__ cnt, int* __restrict__ rowptr) {
  __shared__ int s[1024];
  int t = threadIdx.x;
  s[t] = (t < C_) ? cnt[t] : 0;
  __syncthreads();
  for (int off = 1; off < 1024; off <<= 1) {
    int v = (t >= off) ? s[t - off] : 0;
    __syncthreads();
    s[t] += v;
    __syncthreads();
  }
  if (t < C_) rowptr[t + 1] = s[t];
  if (t == 0) rowptr[0] = 0;
}

__global__ __launch_bounds__(256) void k_scatter(const int* __restrict__ dst,
                                                 const int* __restrict__ rowptr,
                                                 const int* __restrict__ qcnt,
                                                 int* __restrict__ csr_e) {
  const int gw = (blockIdx.x * 256 + threadIdx.x) >> 6;
  const int lane = threadIdx.x & 63;
  const int d = gw >> 4, q = gw & (Q_ - 1);
  int cur = rowptr[d];
  for (int qq = 0; qq < q; ++qq) cur += qcnt[(d << 4) + qq];
  const int e0 = q * (E_ / Q_);
  for (int base = 0; base < E_ / Q_; base += 64) {
    const bool in = (base + lane) < (E_ / Q_);
    const int e = e0 + (in ? base + lane : 0);
    const bool pred = in && (dst[e] == d);
    const unsigned long long mask = __ballot(pred);
    if (pred) csr_e[cur + __popcll(mask & ((1ull << lane) - 1))] = e;
    cur += __popcll(mask);
  }
}

// ---------------- pack: CSR-ordered per-(b,edge) record ----------------
__global__ __launch_bounds__(256) void k_pack(const int* __restrict__ src,
                                              const int* __restrict__ csr_e,
                                              const float* __restrict__ ea0,
                                              int4* __restrict__ pack) {
  const int idx = blockIdx.x * 256 + threadIdx.x;
  const int b = idx / E_, j = idx - b * E_;
  const int e = csr_e[j];
  const int se = src[b * 1000 + (e >> 4)];
  int4 rec;
  rec.x = b * C_ + src[e];
  rec.y = (e & 15) * C_ + se;
  rec.z = __float_as_int(ea0[2 * se]);
  rec.w = __float_as_int(ea0[2 * se + 1]);
  pack[idx] = rec;
}

// ---------------- per-node pre (t=0 only): k, v, wind ----------------
__global__ __launch_bounds__(256) void k_node_pre(
    const float* __restrict__ X, const float* __restrict__ y,
    const float* __restrict__ embW,
    const float* __restrict__ Wk, const float* __restrict__ bk,
    const float* __restrict__ Wv, const float* __restrict__ bv,
    const float* __restrict__ xn_prev,
    float* __restrict__ k, float* __restrict__ v, float2* __restrict__ wind, int t)
{
  __shared__ float sx[4][XF];
  const int local = threadIdx.x >> 6;
  const int h = threadIdx.x & 63;
  const int n = blockIdx.x * 4 + local;
  const int b = n / C_, c = n % C_;
  const float* Xrow = X + (((b * T_TOT + t) * C_ + c) * IN_DIM);

  if (h == 0)       sx[local][0] = xn_prev[n];
  else if (h == 1)  sx[local][1] = y[(b * T_TOT + t) * C_ + c];
  else if (h <= 16) sx[local][h] = Xrow[h - 2];
  if (h == 0) {
    float u10 = Xrow[13] * 3.0f + 0.5f;
    float v10 = Xrow[14] * 3.0f - 0.3f;
    float sp = hypotf(u10, v10);
    float dd = 1.5707963267948966f - atan2f(-v10, -u10);
    if (dd <= 0.f) dd += 6.283185307179586f;
    if (sp == 0.f) dd = 0.f;
    wind[n] = make_float2(sp, dd);
  }
  __syncthreads();

  const float* eW = embW + c * 256;
  float ak = bk[h] + eW[64 + h];
  float av = bv[h] + eW[128 + h];
#pragma unroll
  for (int j = 0; j < XF; ++j) {
    const float xv = sx[local][j];
    ak = fmaf(xv, Wk[j * HID + h], ak);
    av = fmaf(xv, Wv[j * HID + h], av);
  }
  k[(size_t)n * HID + h] = ak;
  v[(size_t)n * HID + h] = av;
}

// ---------------- fused: row-build + q/skip/qproj + attention + MFMA-GRU + t+1 producer ----------------
// block = 16 nodes; wave = 4 nodes (16-lane group per node); grid 1000 = 8*125 XCD swizzle
// r20 structure + latency hoists: hn_in load at top; pack/wind record prefetched ahead.
__global__ __launch_bounds__(256, 4) void k_node_main(
    const int* __restrict__ rowptr, const int4* __restrict__ pack,
    const float* __restrict__ X, const float* __restrict__ y,
    const float* __restrict__ xn_prev,
    const float* __restrict__ embW, const float* __restrict__ gihemb,
    const float* __restrict__ Wq, const float* __restrict__ bq,
    const float* __restrict__ Wskip, const float* __restrict__ bskip,
    const float* __restrict__ Wk, const float* __restrict__ bk,
    const float* __restrict__ Wv, const float* __restrict__ bv,
    const float* __restrict__ We, const float* __restrict__ be,
    const float* __restrict__ kR, const float* __restrict__ vR, const float2* __restrict__ windR,
    float* __restrict__ kW, float* __restrict__ vW, float2* __restrict__ windW,
    const unsigned short* __restrict__ WBhi, const unsigned short* __restrict__ WBlo,
    const float* __restrict__ b_ih, const float* __restrict__ b_hh,
    const float* __restrict__ Wout, const float* __restrict__ bout,
    const float* __restrict__ hn_in, float* __restrict__ hn_out, float* __restrict__ xn_out,
    int t, int last)
{
  __shared__ float sxh[16 * SXP];            // 10240 B
  __shared__ unsigned short sxhH[16 * SHP];  // 5376 B
  __shared__ unsigned short sxhL[16 * SHP];  // 5376 B
  __shared__ float sg[16 * SGP];             // 17152 B

  const int h = threadIdx.x & 63;
  const int wv = threadIdx.x >> 6;
  const int grp = h >> 4, t16 = h & 15;
  const int gbase = h & 48;
  const int lb = ((int)blockIdx.x & 7) * 125 + ((int)blockIdx.x >> 3);
  const int nb0 = wv * 4;
  const int nloc = nb0 + grp;
  const int n = lb * 16 + nloc;
  const int b = n / C_, d = n % C_;

  const int r0 = rowptr[d];
  const int deg = rowptr[d + 1] - r0;
  const int4* packb = pack + (size_t)b * E_;

  // latency hoist 1: own-node hn (consumed post-attention)
  const float4 hv4 = *(const float4*)(hn_in + (size_t)n * HID + t16 * 4);
  // latency hoist 2: chunk-0 pack record + wind (heads the attention dependency chain)
  int4 recP = packb[min(r0 + (t16 < deg ? t16 : 0), E_ - 1)];
  float2 wP = windR[recP.y];

  // ---- build x rows 0..16 into sxh (wave-local; same-wave write->read is HW-ordered) ----
#pragma unroll 1
  for (int i = 0; i < 4; ++i) {
    const int nl = nb0 + i;
    const int ng = lb * 16 + nl;
    const int bb = ng / C_, cc = ng % C_;
    const float* Xrow = X + (((size_t)(bb * T_TOT + t) * C_ + cc) * IN_DIM);
    float* row = &sxh[nl * SXP];
    if (h == 0)       row[0] = xn_prev[ng];
    else if (h == 1)  row[1] = y[(size_t)(bb * T_TOT + t) * C_ + cc];
    else if (h <= 16) row[h] = Xrow[h - 2];
  }

  // ---- own-node q/skip (16-lane float4 GEMV) + qproj butterflies ----
  float4 qv4, sk4, pA, pB;
  {
    const float* eW = embW + d * 256;
    {
      const float4 bq4 = *(const float4*)(bq + t16 * 4);
      const float4 eq4 = *(const float4*)(eW + t16 * 4);
      qv4 = make_float4(bq4.x + eq4.x, bq4.y + eq4.y, bq4.z + eq4.z, bq4.w + eq4.w);
      const float4 bs4 = *(const float4*)(bskip + t16 * 4);
      const float4 es4 = *(const float4*)(eW + 192 + t16 * 4);
      sk4 = make_float4(bs4.x + es4.x, bs4.y + es4.y, bs4.z + es4.z, bs4.w + es4.w);
    }
    const float* row = &sxh[nloc * SXP];
#pragma unroll 4
    for (int j = 0; j < XF; ++j) {
      const float xv = row[j];
      const float4 wq = *(const float4*)(Wq + j * HID + t16 * 4);
      const float4 ws = *(const float4*)(Wskip + j * HID + t16 * 4);
      qv4.x = fmaf(xv, wq.x, qv4.x); qv4.y = fmaf(xv, wq.y, qv4.y);
      qv4.z = fmaf(xv, wq.z, qv4.z); qv4.w = fmaf(xv, wq.w, qv4.w);
      sk4.x = fmaf(xv, ws.x, sk4.x); sk4.y = fmaf(xv, ws.y, sk4.y);
      sk4.z = fmaf(xv, ws.z, sk4.z); sk4.w = fmaf(xv, ws.w, sk4.w);
    }
    const float4 bee = *(const float4*)(be + t16 * 4);
    const float4 w0 = *(const float4*)(We + t16 * 4);
    const float4 w1 = *(const float4*)(We + 64 + t16 * 4);
    const float4 w2 = *(const float4*)(We + 128 + t16 * 4);
    const float4 w3 = *(const float4*)(We + 192 + t16 * 4);
    const float4 w4 = *(const float4*)(We + 256 + t16 * 4);
    float p0 = qv4.x * bee.x + qv4.y * bee.y + qv4.z * bee.z + qv4.w * bee.w;
    float p1 = qv4.x * w0.x + qv4.y * w0.y + qv4.z * w0.z + qv4.w * w0.w;
    float p2 = qv4.x * w1.x + qv4.y * w1.y + qv4.z * w1.z + qv4.w * w1.w;
    float p3 = qv4.x * w2.x + qv4.y * w2.y + qv4.z * w2.z + qv4.w * w2.w;
    float p4 = qv4.x * w3.x + qv4.y * w3.y + qv4.z * w3.z + qv4.w * w3.w;
    float p5 = qv4.x * w4.x + qv4.y * w4.y + qv4.z * w4.z + qv4.w * w4.w;
#pragma unroll
    for (int off = 1; off < 16; off <<= 1) {
      p0 += __shfl_xor(p0, off); p1 += __shfl_xor(p1, off); p2 += __shfl_xor(p2, off);
      p3 += __shfl_xor(p3, off); p4 += __shfl_xor(p4, off); p5 += __shfl_xor(p5, off);
    }
    pA = make_float4(p0, p1, p2, p3);
    pB = make_float4(p4, p5, 0.f, 0.f);
  }

  // ---- attention (own node, 16-lane group), prefetched records ----
  float m = -INFINITY, s = 0.f, S1 = 0.f, S2 = 0.f, S3 = 0.f, S4 = 0.f, S5 = 0.f;
  float4 o4 = make_float4(0.f, 0.f, 0.f, 0.f);

  for (int cb = 0; cb < deg; cb += 16) {
    const int nb = min(16, deg - cb);
    const int4 rec = recP;
    const float2 w2w = wP;
    // prefetch next chunk's record + wind under this chunk's compute
    if (cb + 16 < deg) {
      const int nb2 = min(16, deg - cb - 16);
      recP = packb[r0 + cb + 16 + (t16 < nb2 ? t16 : 0)];
      wP = windR[recP.y];
    }
    const int nsrc = rec.x;
    const float dist = __int_as_float(rec.z), dirc = __int_as_float(rec.w);
    const float sp = w2w.x, wd = w2w.y;
    const float adv = fmaxf(0.f, 3.f * sp * cosf(fabsf(dirc - wd)) / dist);
    float asc = pA.x;
    asc = fmaf(dist, pA.y, asc); asc = fmaf(dirc, pA.z, asc); asc = fmaf(sp, pA.w, asc);
    asc = fmaf(wd, pB.x, asc);   asc = fmaf(adv, pB.y, asc);

    float alpha = -INFINITY;
#pragma unroll 4
    for (int j = 0; j < nb; ++j) {
      const int sl = gbase | j;
      const int nsb = __shfl(nsrc, sl);
      const float4 kv = *(const float4*)(kR + (size_t)nsb * HID + t16 * 4);
      float part = qv4.x * kv.x + qv4.y * kv.y + qv4.z * kv.z + qv4.w * kv.w;
      part += __shfl_xor(part, 1);
      part += __shfl_xor(part, 2);
      part += __shfl_xor(part, 4);
      part += __shfl_xor(part, 8);
      const float af = (part + __shfl(asc, sl)) * 0.125f;   // 1/sqrt(64)
      if (t16 == j) alpha = af;
    }

    float mx = alpha;
    mx = fmaxf(mx, __shfl_xor(mx, 1));
    mx = fmaxf(mx, __shfl_xor(mx, 2));
    mx = fmaxf(mx, __shfl_xor(mx, 4));
    mx = fmaxf(mx, __shfl_xor(mx, 8));
    const float mnew = fmaxf(m, mx);
    const float scale = expf(m - mnew);
    const float a = expf(alpha - mnew);
    float ra = a, q1 = a * dist, q2 = a * dirc, q3 = a * sp, q4 = a * wd, q5 = a * adv;
#pragma unroll
    for (int off = 1; off < 16; off <<= 1) {
      ra += __shfl_xor(ra, off); q1 += __shfl_xor(q1, off); q2 += __shfl_xor(q2, off);
      q3 += __shfl_xor(q3, off); q4 += __shfl_xor(q4, off); q5 += __shfl_xor(q5, off);
    }
    s  = s * scale + ra;  S1 = S1 * scale + q1; S2 = S2 * scale + q2;
    S3 = S3 * scale + q3; S4 = S4 * scale + q4; S5 = S5 * scale + q5;
    o4.x *= scale; o4.y *= scale; o4.z *= scale; o4.w *= scale;
    m = mnew;

#pragma unroll 4
    for (int j = 0; j < nb; ++j) {
      const int sl = gbase | j;
      const float aj = __shfl(a, sl);
      const int nsb = __shfl(nsrc, sl);
      const float4 v4 = *(const float4*)(vR + (size_t)nsb * HID + t16 * 4);
      o4.x = fmaf(aj, v4.x, o4.x); o4.y = fmaf(aj, v4.y, o4.y);
      o4.z = fmaf(aj, v4.z, o4.z); o4.w = fmaf(aj, v4.w, o4.w);
    }
  }

  // reconstruct sum_j a_j*ee_j; fill x_gcn rows 17..80, hn rows 96..159, pads 81..95
  {
    const float4 be4 = *(const float4*)(be + t16 * 4);
    const float4 e0 = *(const float4*)(We + t16 * 4);
    const float4 e1 = *(const float4*)(We + 64 + t16 * 4);
    const float4 e2 = *(const float4*)(We + 128 + t16 * 4);
    const float4 e3 = *(const float4*)(We + 192 + t16 * 4);
    const float4 e4 = *(const float4*)(We + 256 + t16 * 4);
    const float inv = (s > 0.f) ? 1.f / s : 0.f;
    float* xr = &sxh[nloc * SXP];
    float ox, oy, oz, ow;
    ox = s * be4.x; ox = fmaf(S1, e0.x, ox); ox = fmaf(S2, e1.x, ox); ox = fmaf(S3, e2.x, ox); ox = fmaf(S4, e3.x, ox); ox = fmaf(S5, e4.x, ox);
    oy = s * be4.y; oy = fmaf(S1, e0.y, oy); oy = fmaf(S2, e1.y, oy); oy = fmaf(S3, e2.y, oy); oy = fmaf(S4, e3.y, oy); oy = fmaf(S5, e4.y, oy);
    oz = s * be4.z; oz = fmaf(S1, e0.z, oz); oz = fmaf(S2, e1.z, oz); oz = fmaf(S3, e2.z, oz); oz = fmaf(S4, e3.z, oz); oz = fmaf(S5, e4.z, oz);
    ow = s * be4.w; ow = fmaf(S1, e0.w, ow); ow = fmaf(S2, e1.w, ow); ow = fmaf(S3, e2.w, ow); ow = fmaf(S4, e3.w, ow); ow = fmaf(S5, e4.w, ow);
    xr[17 + t16 * 4 + 0] = sigmoidf_(sk4.x + (o4.x + ox) * inv);
    xr[17 + t16 * 4 + 1] = sigmoidf_(sk4.y + (o4.y + oy) * inv);
    xr[17 + t16 * 4 + 2] = sigmoidf_(sk4.z + (o4.z + oz) * inv);
    xr[17 + t16 * 4 + 3] = sigmoidf_(sk4.w + (o4.w + ow) * inv);
    *(float4*)(&xr[HOFF + t16 * 4]) = hv4;
    if (t16 < 15) xr[81 + t16] = 0.f;   // pad rows 81..95
  }

  // ---- convert sxh -> bf16 hi/lo (all 16 nodes x 160 rows) ----
  __syncthreads();
  for (int idx = threadIdx.x; idx < 16 * SXP; idx += 256) {
    const int nd = idx / SXP, rw = idx - nd * SXP;
    const float xv = sxh[idx];
    const unsigned ub = __float_as_uint(xv);
    const float hif = __uint_as_float(ub & 0xffff0000u);
    sxhH[nd * SHP + rw] = (unsigned short)(ub >> 16);
    sxhL[nd * SHP + rw] = (unsigned short)(__float_as_uint(xv - hif) >> 16);
  }
  __syncthreads();

  // ---- MFMA GRU: wave wv handles n-tiles wv*3 .. wv*3+2 ----
  {
    const int lane = h;
    const int aoff = t16 * SHP + grp * 8;   // + ks*32
#pragma unroll 1
    for (int q = 0; q < 3; ++q) {
      const int nt = wv * 3 + q;
      const unsigned short* bhp = WBhi + ((size_t)(nt * 5) * 64 + lane) * 8;
      const unsigned short* blp = WBlo + ((size_t)(nt * 5) * 64 + lane) * 8;
      const int nbase = grp * 4;
      if (nt < 8) {
        f32x4 acc = {0.f, 0.f, 0.f, 0.f};
#pragma unroll 1
        for (int ks = 0; ks < 5; ++ks) {
          const bf16x8 Ah = *(const bf16x8*)(&sxhH[aoff + ks * 32]);
          const bf16x8 Al = *(const bf16x8*)(&sxhL[aoff + ks * 32]);
          const bf16x8 Bh = *(const bf16x8*)(bhp + (size_t)ks * 512);
          const bf16x8 Bl = *(const bf16x8*)(blp + (size_t)ks * 512);
          acc = __builtin_amdgcn_mfma_f32_16x16x32_bf16(Ah, Bh, acc, 0, 0, 0);
          acc = __builtin_amdgcn_mfma_f32_16x16x32_bf16(Ah, Bl, acc, 0, 0, 0);
          acc = __builtin_amdgcn_mfma_f32_16x16x32_bf16(Al, Bh, acc, 0, 0, 0);
        }
        const int gc = nt * 16 + t16;
#pragma unroll
        for (int r = 0; r < 4; ++r) sg[(nbase + r) * SGP + gc] = acc[r];
      } else {
        f32x4 accX = {0.f, 0.f, 0.f, 0.f};
        f32x4 accH = {0.f, 0.f, 0.f, 0.f};
#pragma unroll 1
        for (int ks = 0; ks < 3; ++ks) {
          const bf16x8 Ah = *(const bf16x8*)(&sxhH[aoff + ks * 32]);
          const bf16x8 Al = *(const bf16x8*)(&sxhL[aoff + ks * 32]);
          const bf16x8 Bh = *(const bf16x8*)(bhp + (size_t)ks * 512);
          const bf16x8 Bl = *(const bf16x8*)(blp + (size_t)ks * 512);
          accX = __builtin_amdgcn_mfma_f32_16x16x32_bf16(Ah, Bh, accX, 0, 0, 0);
          accX = __builtin_amdgcn_mfma_f32_16x16x32_bf16(Ah, Bl, accX, 0, 0, 0);
          accX = __builtin_amdgcn_mfma_f32_16x16x32_bf16(Al, Bh, accX, 0, 0, 0);
        }
#pragma unroll 1
        for (int ks = 3; ks < 5; ++ks) {
          const bf16x8 Ah = *(const bf16x8*)(&sxhH[aoff + ks * 32]);
          const bf16x8 Al = *(const bf16x8*)(&sxhL[aoff + ks * 32]);
          const bf16x8 Bh = *(const bf16x8*)(bhp + (size_t)ks * 512);
          const bf16x8 Bl = *(const bf16x8*)(blp + (size_t)ks * 512);
          accH = __builtin_amdgcn_mfma_f32_16x16x32_bf16(Ah, Bh, accH, 0, 0, 0);
          accH = __builtin_amdgcn_mfma_f32_16x16x32_bf16(Ah, Bl, accH, 0, 0, 0);
          accH = __builtin_amdgcn_mfma_f32_16x16x32_bf16(Al, Bh, accH, 0, 0, 0);
        }
        const int gx = 128 + (nt - 8) * 16 + t16;
#pragma unroll
        for (int r = 0; r < 4; ++r) {
          sg[(nbase + r) * SGP + gx] = accX[r];
          sg[(nbase + r) * SGP + gx + 64] = accH[r];
        }
      }
    }
  }
  __syncthreads();

  // ---- pointwise GRU + output head ----
  const float wo = Wout[h];
  const float bout0 = bout[0];
  const float bi0 = b_ih[h] + b_hh[h];
  const float bi1 = b_ih[64 + h] + b_hh[64 + h];
  const float bx = b_ih[128 + h], bh2 = b_hh[128 + h];
#pragma unroll 1
  for (int i = 0; i < 4; ++i) {
    const int nl = nb0 + i;
    const int ng = lb * 16 + nl;
    const int ci = ng % C_;
    const float* ge = gihemb + (size_t)ci * 192;
    const float rg = sigmoidf_(sg[nl * SGP + h] + bi0 + ge[h]);
    const float zg = sigmoidf_(sg[nl * SGP + 64 + h] + bi1 + ge[64 + h]);
    const float gxv = sg[nl * SGP + 128 + h] + bx + ge[128 + h];
    const float ghv = sg[nl * SGP + 192 + h] + bh2;
    const float hv = sxh[nl * SXP + HOFF + h];
    const float nn2 = tanhf(fmaf(rg, ghv, gxv));
    const float hnew = (1.f - zg) * nn2 + zg * hv;
    hn_out[(size_t)ng * HID + h] = hnew;
    float prod = hnew * wo;
#pragma unroll
    for (int off = 1; off < 64; off <<= 1) prod += __shfl_xor(prod, off);
    if (h == 0) {
      const float xnv = prod + bout0;
      xn_out[ng] = xnv;
      sxh[nl * SXP + 0] = xnv;          // LDS row 0 for this dispatch's epilogue
    }
  }

  // ---- epilogue (not last step): produce k/v/wind for t+1 into alternate buffers ----
  if (!last) {
    const int t1 = t + 1;
#pragma unroll 1
    for (int i = 0; i < 4; ++i) {
      const int nl = nb0 + i;
      const int ng = lb * 16 + nl;
      const int bb = ng / C_, cc = ng % C_;
      const float* Xrow = X + (((size_t)(bb * T_TOT + t1) * C_ + cc) * IN_DIM);
      float* row = &sxh[nl * SXP];
      if (h == 1)                 row[1] = y[(size_t)(bb * T_TOT + t1) * C_ + cc];
      else if (h >= 2 && h <= 16) row[h] = Xrow[h - 2];
      if (h == 0) {
        float u10 = Xrow[13] * 3.0f + 0.5f;
        float v10 = Xrow[14] * 3.0f - 0.3f;
        float sp = hypotf(u10, v10);
        float dd = 1.5707963267948966f - atan2f(-v10, -u10);
        if (dd <= 0.f) dd += 6.283185307179586f;
        if (sp == 0.f) dd = 0.f;
        windW[ng] = make_float2(sp, dd);
      }
    }
    {
      const float* eW = embW + d * 256;
      float4 kk4, vv4;
      {
        const float4 bk4 = *(const float4*)(bk + t16 * 4);
        const float4 ek4 = *(const float4*)(eW + 64 + t16 * 4);
        kk4 = make_float4(bk4.x + ek4.x, bk4.y + ek4.y, bk4.z + ek4.z, bk4.w + ek4.w);
        const float4 bv4 = *(const float4*)(bv + t16 * 4);
        const float4 ev4 = *(const float4*)(eW + 128 + t16 * 4);
        vv4 = make_float4(bv4.x + ev4.x, bv4.y + ev4.y, bv4.z + ev4.z, bv4.w + ev4.w);
      }
      const float* row = &sxh[nloc * SXP];
#pragma unroll 1
      for (int j = 0; j < XF; ++j) {
        const float xv = row[j];
        const float4 wk = *(const float4*)(Wk + j * HID + t16 * 4);
        const float4 wvv = *(const float4*)(Wv + j * HID + t16 * 4);
        kk4.x = fmaf(xv, wk.x, kk4.x); kk4.y = fmaf(xv, wk.y, kk4.y);
        kk4.z = fmaf(xv, wk.z, kk4.z); kk4.w = fmaf(xv, wk.w, kk4.w);
        vv4.x = fmaf(xv, wvv.x, vv4.x); vv4.y = fmaf(xv, wvv.y, vv4.y);
        vv4.z = fmaf(xv, wvv.z, vv4.z); vv4.w = fmaf(xv, wvv.w, vv4.w);
      }
      *(float4*)(kW + (size_t)n * HID + t16 * 4) = kk4;
      *(float4*)(vW + (size_t)n * HID + t16 * 4) = vv4;
    }
  }
}

extern "C" void kernel_launch(void* const* d_in, const int* in_sizes, int n_in,
                              void* d_out, int out_size, void* d_ws, size_t ws_size,
                              hipStream_t stream) {
  const float* X      = (const float*)d_in[0];
  const float* y      = (const float*)d_in[1];
  const float* ea0    = (const float*)d_in[2];
  const float* emb    = (const float*)d_in[3];
  const float* Wq     = (const float*)d_in[4];
  const float* bq     = (const float*)d_in[5];
  const float* Wk     = (const float*)d_in[6];
  const float* bk     = (const float*)d_in[7];
  const float* Wv     = (const float*)d_in[8];
  const float* bv     = (const float*)d_in[9];
  const float* We     = (const float*)d_in[10];
  const float* be     = (const float*)d_in[11];
  const float* Wskip  = (const float*)d_in[12];
  const float* bskip  = (const float*)d_in[13];
  const float* W_ih   = (const float*)d_in[14];
  const float* b_ih   = (const float*)d_in[15];
  const float* W_hh   = (const float*)d_in[16];
  const float* b_hh   = (const float*)d_in[17];
  const float* Wout   = (const float*)d_in[18];
  const float* bout   = (const float*)d_in[19];
  const int*   eidx   = (const int*)d_in[20];
  const int* src = eidx;
  const int* dst = eidx + E_;

  float* W = (float*)d_ws;
  size_t off = 0;
  float* kA    = W + off; off += (size_t)N_ * HID;
  float* kB    = W + off; off += (size_t)N_ * HID;
  float* vA    = W + off; off += (size_t)N_ * HID;
  float* vB    = W + off; off += (size_t)N_ * HID;
  float2* wiA  = (float2*)(W + off); off += (size_t)N_ * 2;
  float2* wiB  = (float2*)(W + off); off += (size_t)N_ * 2;
  float* hnA   = W + off; off += (size_t)N_ * HID;
  float* xnA   = W + off; off += N_;
  unsigned short* WBhi = (unsigned short*)(W + off); off += 30720 / 2;
  unsigned short* WBlo = (unsigned short*)(W + off); off += 30720 / 2;
  float* WihT2 = W + off; off += 32 * 192;
  float* embW  = W + off; off += (size_t)C_ * 256;
  float* gihemb= W + off; off += (size_t)C_ * 192;
  off = (off + 3) & ~(size_t)3;      // 16B-align pack
  int4* pack   = (int4*)(W + off); off += (size_t)B_ * E_ * 4;
  int* cnt     = (int*)(W + off); off += C_;
  int* rowptr  = (int*)(W + off); off += C_ + 1;
  int* qcnt    = (int*)(W + off); off += C_ * Q_;
  int* csr_e   = (int*)(W + off); off += E_;

  k_init<<<1024, 256, 0, stream>>>(hnA, xnA, cnt);
  k_prep<<<(30720 + 32 * 192 + 255) / 256, 256, 0, stream>>>(W_ih, W_hh, WBhi, WBlo, WihT2);
  k_embfold<<<C_, 256, 0, stream>>>(emb, Wq, Wk, Wv, Wskip, WihT2, embW, gihemb);
  k_count<<<C_ * Q_ / 4, 256, 0, stream>>>(dst, qcnt, cnt);
  k_scan<<<1, 1024, 0, stream>>>(cnt, rowptr);
  k_scatter<<<C_ * Q_ / 4, 256, 0, stream>>>(dst, rowptr, qcnt, csr_e);
  k_pack<<<B_ * E_ / 256, 256, 0, stream>>>(src, csr_e, ea0, pack);

  float* hn_final = (float*)d_out;
  float* xn_final = (float*)d_out + (size_t)N_ * HID;

  // t=0 producer
  k_node_pre<<<N_ / 4, 256, 0, stream>>>(X, y, embW, Wk, bk, Wv, bv,
                                         xnA, kA, vA, wiA, 0);

  for (int t = 0; t < HIST; ++t) {
    const bool last = (t == HIST - 1);
    const bool even = ((t & 1) == 0);
    k_node_main<<<N_ / 16, 256, 0, stream>>>(rowptr, pack, X, y, xnA, embW, gihemb,
                                             Wq, bq, Wskip, bskip, Wk, bk, Wv, bv, We, be,
                                             even ? kA : kB, even ? vA : vB, even ? wiA : wiB,
                                             even ? kB : kA, even ? vB : vA, even ? wiB : wiA,
                                             WBhi, WBlo,
                                             b_ih, b_hh, Wout, bout,
                                             hnA,
                                             last ? hn_final : hnA,
                                             last ? xn_final : xnA,
                                             t, last ? 1 : 0);
  }
}

// Round 23
// 375.388 us; speedup vs baseline: 1.3932x; 1.0540x over previous
//
#include <hip/hip_runtime.h>
#include <math.h>

#define B_ 16
#define T_TOT 16
#define C_ 1000
#define N_ 16000          // B_*C_
#define E_ 16000
#define HID 64
#define EMB 32
#define IN_DIM 16
#define XF 17             // dynamic x rows (xn, y, 15 feats); emb rows folded
#define HIST 8
#define SXP 160           // sxh row pitch: 17 dyn + 64 gcn + 15 pad + 64 hn = 160 = 5*32
#define HOFF 96           // hn rows 96..159 (K-steps 3,4); x-side rows 0..95 (K-steps 0..2)
#define SHP 168           // bf16 hi/lo row pitch (16B-aligned rows)
#define SGP 268           // gates buffer pitch
#define Q_ 16             // scatter partitions

typedef __attribute__((ext_vector_type(8))) short bf16x8;
typedef __attribute__((ext_vector_type(4))) float f32x4;

__device__ __forceinline__ float sigmoidf_(float x) { return 1.f / (1.f + expf(-x)); }

// ---------------- merged setup: init hn/xn | prep WB/WihT2 | count qcnt ----------------
// three independent jobs on disjoint block ranges (no cross-job ordering needed:
// count no longer atomics into cnt -- scan sums qcnt partials itself)
__global__ __launch_bounds__(256) void k_setup(
    const float* __restrict__ W_ih, const float* __restrict__ W_hh,
    const int* __restrict__ dst,
    float* __restrict__ hn, float* __restrict__ xn,
    unsigned short* __restrict__ WBhi, unsigned short* __restrict__ WBlo,
    float* __restrict__ WihT2, int* __restrict__ qcnt)
{
  const int blk = blockIdx.x;
  if (blk < 1024) {
    // job A: zero hn, xn
    const int total = N_ * HID + N_;
    for (int i = blk * 256 + threadIdx.x; i < total; i += 1024 * 256) {
      if (i < N_ * HID) hn[i] = 0.f;
      else xn[i - N_ * HID] = 0.f;
    }
  } else if (blk < 1024 + 144) {
    // job B: B-fragment-ordered bf16 hi/lo GRU weights + WihT2
    int i = (blk - 1024) * 256 + threadIdx.x;
    if (i < 30720) {
      const int j = i & 7;
      const int l = (i >> 3) & 63;
      const int ksnt = i >> 9;
      const int ks = ksnt % 5, nt = ksnt / 5;
      const int k = ks * 32 + (l >> 4) * 8 + j;
      const int g = nt * 16 + (l & 15);
      float w = 0.f;
      if (k < 17) w = W_ih[g * 113 + k];
      else if (k < 81) w = W_ih[g * 113 + 49 + (k - 17)];
      else if (k >= HOFF) w = W_hh[g * 64 + (k - HOFF)];
      const unsigned ub = __float_as_uint(w);
      const float hif = __uint_as_float(ub & 0xffff0000u);
      WBhi[i] = (unsigned short)(ub >> 16);
      WBlo[i] = (unsigned short)(__float_as_uint(w - hif) >> 16);
    } else if (i < 30720 + 32 * 192) {
      int i2 = i - 30720;
      int j2 = i2 / 192, g = i2 - j2 * 192;
      WihT2[i2] = W_ih[g * 113 + 17 + j2];
    }
  } else {
    // job C: per-(d,q) edge counts (no atomics)
    const int gw = ((blk - 1168) * 256 + threadIdx.x) >> 6;
    const int lane = threadIdx.x & 63;
    const int d = gw >> 4, q = gw & (Q_ - 1);
    const int e0 = q * (E_ / Q_);
    int cur = 0;
    for (int base = 0; base < E_ / Q_; base += 64) {
      const bool in = (base + lane) < (E_ / Q_);
      const int e = e0 + (in ? base + lane : 0);
      cur += __popcll(__ballot(in && (dst[e] == d)));
    }
    if (lane == 0) qcnt[(d << 4) + q] = cur;
  }
}

// ---------------- embfold (once) ----------------
__global__ __launch_bounds__(256) void k_embfold(
    const float* __restrict__ emb_table,
    const float* __restrict__ Wq, const float* __restrict__ Wk,
    const float* __restrict__ Wv, const float* __restrict__ Wskip,
    const float* __restrict__ WihT2,
    float* __restrict__ embW, float* __restrict__ gihemb) {
  __shared__ float se[EMB];
  const int c = blockIdx.x;
  const int t = threadIdx.x;
  if (t < EMB) se[t] = emb_table[c * EMB + t];
  __syncthreads();
  const int mat = t >> 6, h = t & 63;
  const float* Wm = (mat == 0) ? Wq : (mat == 1) ? Wk : (mat == 2) ? Wv : Wskip;
  float acc = 0.f;
#pragma unroll
  for (int j = 0; j < EMB; ++j) acc = fmaf(se[j], Wm[(17 + j) * HID + h], acc);
  embW[c * 256 + t] = acc;
  if (t < 192) {
    float a2 = 0.f;
#pragma unroll
    for (int j = 0; j < EMB; ++j) a2 = fmaf(se[j], WihT2[j * 192 + t], a2);
    gihemb[c * 192 + t] = a2;
  }
}

// ---------------- scan: rowptr from qcnt partial sums ----------------
__global__ __launch_bounds__(1024) void k_scan(const int* __restrict__ qcnt, int* __restrict__ rowptr) {
  __shared__ int s[1024];
  int t = threadIdx.x;
  int acc = 0;
  if (t < C_) {
#pragma unroll
    for (int q = 0; q < Q_; ++q) acc += qcnt[t * Q_ + q];
  }
  s[t] = acc;
  __syncthreads();
  for (int off = 1; off < 1024; off <<= 1) {
    int v = (t >= off) ? s[t - off] : 0;
    __syncthreads();
    s[t] += v;
    __syncthreads();
  }
  if (t < C_) rowptr[t + 1] = s[t];
  if (t == 0) rowptr[0] = 0;
}

__global__ __launch_bounds__(256) void k_scatter(const int* __restrict__ dst,
                                                 const int* __restrict__ rowptr,
                                                 const int* __restrict__ qcnt,
                                                 int* __restrict__ csr_e) {
  const int gw = (blockIdx.x * 256 + threadIdx.x) >> 6;
  const int lane = threadIdx.x & 63;
  const int d = gw >> 4, q = gw & (Q_ - 1);
  int cur = rowptr[d];
  for (int qq = 0; qq < q; ++qq) cur += qcnt[(d << 4) + qq];
  const int e0 = q * (E_ / Q_);
  for (int base = 0; base < E_ / Q_; base += 64) {
    const bool in = (base + lane) < (E_ / Q_);
    const int e = e0 + (in ? base + lane : 0);
    const bool pred = in && (dst[e] == d);
    const unsigned long long mask = __ballot(pred);
    if (pred) csr_e[cur + __popcll(mask & ((1ull << lane) - 1))] = e;
    cur += __popcll(mask);
  }
}

// ---------------- pack: CSR-ordered per-(b,edge) record ----------------
__global__ __launch_bounds__(256) void k_pack(const int* __restrict__ src,
                                              const int* __restrict__ csr_e,
                                              const float* __restrict__ ea0,
                                              int4* __restrict__ pack) {
  const int idx = blockIdx.x * 256 + threadIdx.x;
  const int b = idx / E_, j = idx - b * E_;
  const int e = csr_e[j];
  const int se = src[b * 1000 + (e >> 4)];
  int4 rec;
  rec.x = b * C_ + src[e];
  rec.y = (e & 15) * C_ + se;
  rec.z = __float_as_int(ea0[2 * se]);
  rec.w = __float_as_int(ea0[2 * se + 1]);
  pack[idx] = rec;
}

// ---------------- per-node pre (t=0 only): k, v, wind ----------------
__global__ __launch_bounds__(256) void k_node_pre(
    const float* __restrict__ X, const float* __restrict__ y,
    const float* __restrict__ embW,
    const float* __restrict__ Wk, const float* __restrict__ bk,
    const float* __restrict__ Wv, const float* __restrict__ bv,
    const float* __restrict__ xn_prev,
    float* __restrict__ k, float* __restrict__ v, float2* __restrict__ wind, int t)
{
  __shared__ float sx[4][XF];
  const int local = threadIdx.x >> 6;
  const int h = threadIdx.x & 63;
  const int n = blockIdx.x * 4 + local;
  const int b = n / C_, c = n % C_;
  const float* Xrow = X + (((b * T_TOT + t) * C_ + c) * IN_DIM);

  if (h == 0)       sx[local][0] = xn_prev[n];
  else if (h == 1)  sx[local][1] = y[(b * T_TOT + t) * C_ + c];
  else if (h <= 16) sx[local][h] = Xrow[h - 2];
  if (h == 0) {
    float u10 = Xrow[13] * 3.0f + 0.5f;
    float v10 = Xrow[14] * 3.0f - 0.3f;
    float sp = hypotf(u10, v10);
    float dd = 1.5707963267948966f - atan2f(-v10, -u10);
    if (dd <= 0.f) dd += 6.283185307179586f;
    if (sp == 0.f) dd = 0.f;
    wind[n] = make_float2(sp, dd);
  }
  __syncthreads();

  const float* eW = embW + c * 256;
  float ak = bk[h] + eW[64 + h];
  float av = bv[h] + eW[128 + h];
#pragma unroll
  for (int j = 0; j < XF; ++j) {
    const float xv = sx[local][j];
    ak = fmaf(xv, Wk[j * HID + h], ak);
    av = fmaf(xv, Wv[j * HID + h], av);
  }
  k[(size_t)n * HID + h] = ak;
  v[(size_t)n * HID + h] = av;
}

// ---------------- fused: row-build + q/skip/qproj + attention + MFMA-GRU + t+1 producer ----------------
// block = 16 nodes; wave = 4 nodes (16-lane group per node); grid 1000 = 8*125 XCD swizzle
// (exact r20 structure -- measured best)
__global__ __launch_bounds__(256, 4) void k_node_main(
    const int* __restrict__ rowptr, const int4* __restrict__ pack,
    const float* __restrict__ X, const float* __restrict__ y,
    const float* __restrict__ xn_prev,
    const float* __restrict__ embW, const float* __restrict__ gihemb,
    const float* __restrict__ Wq, const float* __restrict__ bq,
    const float* __restrict__ Wskip, const float* __restrict__ bskip,
    const float* __restrict__ Wk, const float* __restrict__ bk,
    const float* __restrict__ Wv, const float* __restrict__ bv,
    const float* __restrict__ We, const float* __restrict__ be,
    const float* __restrict__ kR, const float* __restrict__ vR, const float2* __restrict__ windR,
    float* __restrict__ kW, float* __restrict__ vW, float2* __restrict__ windW,
    const unsigned short* __restrict__ WBhi, const unsigned short* __restrict__ WBlo,
    const float* __restrict__ b_ih, const float* __restrict__ b_hh,
    const float* __restrict__ Wout, const float* __restrict__ bout,
    const float* __restrict__ hn_in, float* __restrict__ hn_out, float* __restrict__ xn_out,
    int t, int last)
{
  __shared__ float sxh[16 * SXP];            // 10240 B
  __shared__ unsigned short sxhH[16 * SHP];  // 5376 B
  __shared__ unsigned short sxhL[16 * SHP];  // 5376 B
  __shared__ float sg[16 * SGP];             // 17152 B

  const int h = threadIdx.x & 63;
  const int wv = threadIdx.x >> 6;
  const int grp = h >> 4, t16 = h & 15;
  const int gbase = h & 48;
  const int lb = ((int)blockIdx.x & 7) * 125 + ((int)blockIdx.x >> 3);
  const int nb0 = wv * 4;
  const int nloc = nb0 + grp;
  const int n = lb * 16 + nloc;
  const int b = n / C_, d = n % C_;

  const int r0 = rowptr[d];
  const int deg = rowptr[d + 1] - r0;
  const int4* packb = pack + (size_t)b * E_;

  // ---- build x rows 0..16 into sxh (wave-local; same-wave write->read is HW-ordered) ----
#pragma unroll 1
  for (int i = 0; i < 4; ++i) {
    const int nl = nb0 + i;
    const int ng = lb * 16 + nl;
    const int bb = ng / C_, cc = ng % C_;
    const float* Xrow = X + (((size_t)(bb * T_TOT + t) * C_ + cc) * IN_DIM);
    float* row = &sxh[nl * SXP];
    if (h == 0)       row[0] = xn_prev[ng];
    else if (h == 1)  row[1] = y[(size_t)(bb * T_TOT + t) * C_ + cc];
    else if (h <= 16) row[h] = Xrow[h - 2];
  }

  // ---- own-node q/skip (16-lane float4 GEMV) + qproj butterflies ----
  float4 qv4, sk4, pA, pB;
  {
    const float* eW = embW + d * 256;
    {
      const float4 bq4 = *(const float4*)(bq + t16 * 4);
      const float4 eq4 = *(const float4*)(eW + t16 * 4);
      qv4 = make_float4(bq4.x + eq4.x, bq4.y + eq4.y, bq4.z + eq4.z, bq4.w + eq4.w);
      const float4 bs4 = *(const float4*)(bskip + t16 * 4);
      const float4 es4 = *(const float4*)(eW + 192 + t16 * 4);
      sk4 = make_float4(bs4.x + es4.x, bs4.y + es4.y, bs4.z + es4.z, bs4.w + es4.w);
    }
    const float* row = &sxh[nloc * SXP];
#pragma unroll 4
    for (int j = 0; j < XF; ++j) {
      const float xv = row[j];
      const float4 wq = *(const float4*)(Wq + j * HID + t16 * 4);
      const float4 ws = *(const float4*)(Wskip + j * HID + t16 * 4);
      qv4.x = fmaf(xv, wq.x, qv4.x); qv4.y = fmaf(xv, wq.y, qv4.y);
      qv4.z = fmaf(xv, wq.z, qv4.z); qv4.w = fmaf(xv, wq.w, qv4.w);
      sk4.x = fmaf(xv, ws.x, sk4.x); sk4.y = fmaf(xv, ws.y, sk4.y);
      sk4.z = fmaf(xv, ws.z, sk4.z); sk4.w = fmaf(xv, ws.w, sk4.w);
    }
    const float4 bee = *(const float4*)(be + t16 * 4);
    const float4 w0 = *(const float4*)(We + t16 * 4);
    const float4 w1 = *(const float4*)(We + 64 + t16 * 4);
    const float4 w2 = *(const float4*)(We + 128 + t16 * 4);
    const float4 w3 = *(const float4*)(We + 192 + t16 * 4);
    const float4 w4 = *(const float4*)(We + 256 + t16 * 4);
    float p0 = qv4.x * bee.x + qv4.y * bee.y + qv4.z * bee.z + qv4.w * bee.w;
    float p1 = qv4.x * w0.x + qv4.y * w0.y + qv4.z * w0.z + qv4.w * w0.w;
    float p2 = qv4.x * w1.x + qv4.y * w1.y + qv4.z * w1.z + qv4.w * w1.w;
    float p3 = qv4.x * w2.x + qv4.y * w2.y + qv4.z * w2.z + qv4.w * w2.w;
    float p4 = qv4.x * w3.x + qv4.y * w3.y + qv4.z * w3.z + qv4.w * w3.w;
    float p5 = qv4.x * w4.x + qv4.y * w4.y + qv4.z * w4.z + qv4.w * w4.w;
#pragma unroll
    for (int off = 1; off < 16; off <<= 1) {
      p0 += __shfl_xor(p0, off); p1 += __shfl_xor(p1, off); p2 += __shfl_xor(p2, off);
      p3 += __shfl_xor(p3, off); p4 += __shfl_xor(p4, off); p5 += __shfl_xor(p5, off);
    }
    pA = make_float4(p0, p1, p2, p3);
    pB = make_float4(p4, p5, 0.f, 0.f);
  }

  // ---- attention (own node, 16-lane group) ----
  float m = -INFINITY, s = 0.f, S1 = 0.f, S2 = 0.f, S3 = 0.f, S4 = 0.f, S5 = 0.f;
  float4 o4 = make_float4(0.f, 0.f, 0.f, 0.f);

  for (int cb = 0; cb < deg; cb += 16) {
    const int nb = min(16, deg - cb);
    const int4 rec = packb[r0 + cb + (t16 < nb ? t16 : 0)];
    const int nsrc = rec.x;
    const float dist = __int_as_float(rec.z), dirc = __int_as_float(rec.w);
    const float2 w2w = windR[rec.y];
    const float sp = w2w.x, wd = w2w.y;
    const float adv = fmaxf(0.f, 3.f * sp * cosf(fabsf(dirc - wd)) / dist);
    float asc = pA.x;
    asc = fmaf(dist, pA.y, asc); asc = fmaf(dirc, pA.z, asc); asc = fmaf(sp, pA.w, asc);
    asc = fmaf(wd, pB.x, asc);   asc = fmaf(adv, pB.y, asc);

    float alpha = -INFINITY;
#pragma unroll 4
    for (int j = 0; j < nb; ++j) {
      const int sl = gbase | j;
      const int nsb = __shfl(nsrc, sl);
      const float4 kv = *(const float4*)(kR + (size_t)nsb * HID + t16 * 4);
      float part = qv4.x * kv.x + qv4.y * kv.y + qv4.z * kv.z + qv4.w * kv.w;
      part += __shfl_xor(part, 1);
      part += __shfl_xor(part, 2);
      part += __shfl_xor(part, 4);
      part += __shfl_xor(part, 8);
      const float af = (part + __shfl(asc, sl)) * 0.125f;   // 1/sqrt(64)
      if (t16 == j) alpha = af;
    }

    float mx = alpha;
    mx = fmaxf(mx, __shfl_xor(mx, 1));
    mx = fmaxf(mx, __shfl_xor(mx, 2));
    mx = fmaxf(mx, __shfl_xor(mx, 4));
    mx = fmaxf(mx, __shfl_xor(mx, 8));
    const float mnew = fmaxf(m, mx);
    const float scale = expf(m - mnew);
    const float a = expf(alpha - mnew);
    float ra = a, q1 = a * dist, q2 = a * dirc, q3 = a * sp, q4 = a * wd, q5 = a * adv;
#pragma unroll
    for (int off = 1; off < 16; off <<= 1) {
      ra += __shfl_xor(ra, off); q1 += __shfl_xor(q1, off); q2 += __shfl_xor(q2, off);
      q3 += __shfl_xor(q3, off); q4 += __shfl_xor(q4, off); q5 += __shfl_xor(q5, off);
    }
    s  = s * scale + ra;  S1 = S1 * scale + q1; S2 = S2 * scale + q2;
    S3 = S3 * scale + q3; S4 = S4 * scale + q4; S5 = S5 * scale + q5;
    o4.x *= scale; o4.y *= scale; o4.z *= scale; o4.w *= scale;
    m = mnew;

#pragma unroll 4
    for (int j = 0; j < nb; ++j) {
      const int sl = gbase | j;
      const float aj = __shfl(a, sl);
      const int nsb = __shfl(nsrc, sl);
      const float4 v4 = *(const float4*)(vR + (size_t)nsb * HID + t16 * 4);
      o4.x = fmaf(aj, v4.x, o4.x); o4.y = fmaf(aj, v4.y, o4.y);
      o4.z = fmaf(aj, v4.z, o4.z); o4.w = fmaf(aj, v4.w, o4.w);
    }
  }

  // reconstruct sum_j a_j*ee_j; fill x_gcn rows 17..80, hn rows 96..159, pads 81..95
  {
    const float4 be4 = *(const float4*)(be + t16 * 4);
    const float4 e0 = *(const float4*)(We + t16 * 4);
    const float4 e1 = *(const float4*)(We + 64 + t16 * 4);
    const float4 e2 = *(const float4*)(We + 128 + t16 * 4);
    const float4 e3 = *(const float4*)(We + 192 + t16 * 4);
    const float4 e4 = *(const float4*)(We + 256 + t16 * 4);
    const float inv = (s > 0.f) ? 1.f / s : 0.f;
    float* xr = &sxh[nloc * SXP];
    float ox, oy, oz, ow;
    ox = s * be4.x; ox = fmaf(S1, e0.x, ox); ox = fmaf(S2, e1.x, ox); ox = fmaf(S3, e2.x, ox); ox = fmaf(S4, e3.x, ox); ox = fmaf(S5, e4.x, ox);
    oy = s * be4.y; oy = fmaf(S1, e0.y, oy); oy = fmaf(S2, e1.y, oy); oy = fmaf(S3, e2.y, oy); oy = fmaf(S4, e3.y, oy); oy = fmaf(S5, e4.y, oy);
    oz = s * be4.z; oz = fmaf(S1, e0.z, oz); oz = fmaf(S2, e1.z, oz); oz = fmaf(S3, e2.z, oz); oz = fmaf(S4, e3.z, oz); oz = fmaf(S5, e4.z, oz);
    ow = s * be4.w; ow = fmaf(S1, e0.w, ow); ow = fmaf(S2, e1.w, ow); ow = fmaf(S3, e2.w, ow); ow = fmaf(S4, e3.w, ow); ow = fmaf(S5, e4.w, ow);
    xr[17 + t16 * 4 + 0] = sigmoidf_(sk4.x + (o4.x + ox) * inv);
    xr[17 + t16 * 4 + 1] = sigmoidf_(sk4.y + (o4.y + oy) * inv);
    xr[17 + t16 * 4 + 2] = sigmoidf_(sk4.z + (o4.z + oz) * inv);
    xr[17 + t16 * 4 + 3] = sigmoidf_(sk4.w + (o4.w + ow) * inv);
    const float4 hv4 = *(const float4*)(hn_in + (size_t)n * HID + t16 * 4);
    *(float4*)(&xr[HOFF + t16 * 4]) = hv4;
    if (t16 < 15) xr[81 + t16] = 0.f;   // pad rows 81..95
  }

  // ---- convert sxh -> bf16 hi/lo (all 16 nodes x 160 rows) ----
  __syncthreads();
  for (int idx = threadIdx.x; idx < 16 * SXP; idx += 256) {
    const int nd = idx / SXP, rw = idx - nd * SXP;
    const float xv = sxh[idx];
    const unsigned ub = __float_as_uint(xv);
    const float hif = __uint_as_float(ub & 0xffff0000u);
    sxhH[nd * SHP + rw] = (unsigned short)(ub >> 16);
    sxhL[nd * SHP + rw] = (unsigned short)(__float_as_uint(xv - hif) >> 16);
  }
  __syncthreads();

  // ---- MFMA GRU: wave wv handles n-tiles wv*3 .. wv*3+2 ----
  {
    const int lane = h;
    const int aoff = t16 * SHP + grp * 8;   // + ks*32
#pragma unroll 1
    for (int q = 0; q < 3; ++q) {
      const int nt = wv * 3 + q;
      const unsigned short* bhp = WBhi + ((size_t)(nt * 5) * 64 + lane) * 8;
      const unsigned short* blp = WBlo + ((size_t)(nt * 5) * 64 + lane) * 8;
      const int nbase = grp * 4;
      if (nt < 8) {
        f32x4 acc = {0.f, 0.f, 0.f, 0.f};
#pragma unroll 1
        for (int ks = 0; ks < 5; ++ks) {
          const bf16x8 Ah = *(const bf16x8*)(&sxhH[aoff + ks * 32]);
          const bf16x8 Al = *(const bf16x8*)(&sxhL[aoff + ks * 32]);
          const bf16x8 Bh = *(const bf16x8*)(bhp + (size_t)ks * 512);
          const bf16x8 Bl = *(const bf16x8*)(blp + (size_t)ks * 512);
          acc = __builtin_amdgcn_mfma_f32_16x16x32_bf16(Ah, Bh, acc, 0, 0, 0);
          acc = __builtin_amdgcn_mfma_f32_16x16x32_bf16(Ah, Bl, acc, 0, 0, 0);
          acc = __builtin_amdgcn_mfma_f32_16x16x32_bf16(Al, Bh, acc, 0, 0, 0);
        }
        const int gc = nt * 16 + t16;
#pragma unroll
        for (int r = 0; r < 4; ++r) sg[(nbase + r) * SGP + gc] = acc[r];
      } else {
        f32x4 accX = {0.f, 0.f, 0.f, 0.f};
        f32x4 accH = {0.f, 0.f, 0.f, 0.f};
#pragma unroll 1
        for (int ks = 0; ks < 3; ++ks) {
          const bf16x8 Ah = *(const bf16x8*)(&sxhH[aoff + ks * 32]);
          const bf16x8 Al = *(const bf16x8*)(&sxhL[aoff + ks * 32]);
          const bf16x8 Bh = *(const bf16x8*)(bhp + (size_t)ks * 512);
          const bf16x8 Bl = *(const bf16x8*)(blp + (size_t)ks * 512);
          accX = __builtin_amdgcn_mfma_f32_16x16x32_bf16(Ah, Bh, accX, 0, 0, 0);
          accX = __builtin_amdgcn_mfma_f32_16x16x32_bf16(Ah, Bl, accX, 0, 0, 0);
          accX = __builtin_amdgcn_mfma_f32_16x16x32_bf16(Al, Bh, accX, 0, 0, 0);
        }
#pragma unroll 1
        for (int ks = 3; ks < 5; ++ks) {
          const bf16x8 Ah = *(const bf16x8*)(&sxhH[aoff + ks * 32]);
          const bf16x8 Al = *(const bf16x8*)(&sxhL[aoff + ks * 32]);
          const bf16x8 Bh = *(const bf16x8*)(bhp + (size_t)ks * 512);
          const bf16x8 Bl = *(const bf16x8*)(blp + (size_t)ks * 512);
          accH = __builtin_amdgcn_mfma_f32_16x16x32_bf16(Ah, Bh, accH, 0, 0, 0);
          accH = __builtin_amdgcn_mfma_f32_16x16x32_bf16(Ah, Bl, accH, 0, 0, 0);
          accH = __builtin_amdgcn_mfma_f32_16x16x32_bf16(Al, Bh, accH, 0, 0, 0);
        }
        const int gx = 128 + (nt - 8) * 16 + t16;
#pragma unroll
        for (int r = 0; r < 4; ++r) {
          sg[(nbase + r) * SGP + gx] = accX[r];
          sg[(nbase + r) * SGP + gx + 64] = accH[r];
        }
      }
    }
  }
  __syncthreads();

  // ---- pointwise GRU + output head ----
  const float wo = Wout[h];
  const float bout0 = bout[0];
  const float bi0 = b_ih[h] + b_hh[h];
  const float bi1 = b_ih[64 + h] + b_hh[64 + h];
  const float bx = b_ih[128 + h], bh2 = b_hh[128 + h];
#pragma unroll 1
  for (int i = 0; i < 4; ++i) {
    const int nl = nb0 + i;
    const int ng = lb * 16 + nl;
    const int ci = ng % C_;
    const float* ge = gihemb + (size_t)ci * 192;
    const float rg = sigmoidf_(sg[nl * SGP + h] + bi0 + ge[h]);
    const float zg = sigmoidf_(sg[nl * SGP + 64 + h] + bi1 + ge[64 + h]);
    const float gxv = sg[nl * SGP + 128 + h] + bx + ge[128 + h];
    const float ghv = sg[nl * SGP + 192 + h] + bh2;
    const float hv = sxh[nl * SXP + HOFF + h];
    const float nn2 = tanhf(fmaf(rg, ghv, gxv));
    const float hnew = (1.f - zg) * nn2 + zg * hv;
    hn_out[(size_t)ng * HID + h] = hnew;
    float prod = hnew * wo;
#pragma unroll
    for (int off = 1; off < 64; off <<= 1) prod += __shfl_xor(prod, off);
    if (h == 0) {
      const float xnv = prod + bout0;
      xn_out[ng] = xnv;
      sxh[nl * SXP + 0] = xnv;          // LDS row 0 for this dispatch's epilogue
    }
  }

  // ---- epilogue (not last step): produce k/v/wind for t+1 into alternate buffers ----
  if (!last) {
    const int t1 = t + 1;
#pragma unroll 1
    for (int i = 0; i < 4; ++i) {
      const int nl = nb0 + i;
      const int ng = lb * 16 + nl;
      const int bb = ng / C_, cc = ng % C_;
      const float* Xrow = X + (((size_t)(bb * T_TOT + t1) * C_ + cc) * IN_DIM);
      float* row = &sxh[nl * SXP];
      if (h == 1)                 row[1] = y[(size_t)(bb * T_TOT + t1) * C_ + cc];
      else if (h >= 2 && h <= 16) row[h] = Xrow[h - 2];
      if (h == 0) {
        float u10 = Xrow[13] * 3.0f + 0.5f;
        float v10 = Xrow[14] * 3.0f - 0.3f;
        float sp = hypotf(u10, v10);
        float dd = 1.5707963267948966f - atan2f(-v10, -u10);
        if (dd <= 0.f) dd += 6.283185307179586f;
        if (sp == 0.f) dd = 0.f;
        windW[ng] = make_float2(sp, dd);
      }
    }
    {
      const float* eW = embW + d * 256;
      float4 kk4, vv4;
      {
        const float4 bk4 = *(const float4*)(bk + t16 * 4);
        const float4 ek4 = *(const float4*)(eW + 64 + t16 * 4);
        kk4 = make_float4(bk4.x + ek4.x, bk4.y + ek4.y, bk4.z + ek4.z, bk4.w + ek4.w);
        const float4 bv4 = *(const float4*)(bv + t16 * 4);
        const float4 ev4 = *(const float4*)(eW + 128 + t16 * 4);
        vv4 = make_float4(bv4.x + ev4.x, bv4.y + ev4.y, bv4.z + ev4.z, bv4.w + ev4.w);
      }
      const float* row = &sxh[nloc * SXP];
#pragma unroll 1
      for (int j = 0; j < XF; ++j) {
        const float xv = row[j];
        const float4 wk = *(const float4*)(Wk + j * HID + t16 * 4);
        const float4 wvv = *(const float4*)(Wv + j * HID + t16 * 4);
        kk4.x = fmaf(xv, wk.x, kk4.x); kk4.y = fmaf(xv, wk.y, kk4.y);
        kk4.z = fmaf(xv, wk.z, kk4.z); kk4.w = fmaf(xv, wk.w, kk4.w);
        vv4.x = fmaf(xv, wvv.x, vv4.x); vv4.y = fmaf(xv, wvv.y, vv4.y);
        vv4.z = fmaf(xv, wvv.z, vv4.z); vv4.w = fmaf(xv, wvv.w, vv4.w);
      }
      *(float4*)(kW + (size_t)n * HID + t16 * 4) = kk4;
      *(float4*)(vW + (size_t)n * HID + t16 * 4) = vv4;
    }
  }
}

extern "C" void kernel_launch(void* const* d_in, const int* in_sizes, int n_in,
                              void* d_out, int out_size, void* d_ws, size_t ws_size,
                              hipStream_t stream) {
  const float* X      = (const float*)d_in[0];
  const float* y      = (const float*)d_in[1];
  const float* ea0    = (const float*)d_in[2];
  const float* emb    = (const float*)d_in[3];
  const float* Wq     = (const float*)d_in[4];
  const float* bq     = (const float*)d_in[5];
  const float* Wk     = (const float*)d_in[6];
  const float* bk     = (const float*)d_in[7];
  const float* Wv     = (const float*)d_in[8];
  const float* bv     = (const float*)d_in[9];
  const float* We     = (const float*)d_in[10];
  const float* be     = (const float*)d_in[11];
  const float* Wskip  = (const float*)d_in[12];
  const float* bskip  = (const float*)d_in[13];
  const float* W_ih   = (const float*)d_in[14];
  const float* b_ih   = (const float*)d_in[15];
  const float* W_hh   = (const float*)d_in[16];
  const float* b_hh   = (const float*)d_in[17];
  const float* Wout   = (const float*)d_in[18];
  const float* bout   = (const float*)d_in[19];
  const int*   eidx   = (const int*)d_in[20];
  const int* src = eidx;
  const int* dst = eidx + E_;

  float* W = (float*)d_ws;
  size_t off = 0;
  float* kA    = W + off; off += (size_t)N_ * HID;
  float* kB    = W + off; off += (size_t)N_ * HID;
  float* vA    = W + off; off += (size_t)N_ * HID;
  float* vB    = W + off; off += (size_t)N_ * HID;
  float2* wiA  = (float2*)(W + off); off += (size_t)N_ * 2;
  float2* wiB  = (float2*)(W + off); off += (size_t)N_ * 2;
  float* hnA   = W + off; off += (size_t)N_ * HID;
  float* xnA   = W + off; off += N_;
  unsigned short* WBhi = (unsigned short*)(W + off); off += 30720 / 2;
  unsigned short* WBlo = (unsigned short*)(W + off); off += 30720 / 2;
  float* WihT2 = W + off; off += 32 * 192;
  float* embW  = W + off; off += (size_t)C_ * 256;
  float* gihemb= W + off; off += (size_t)C_ * 192;
  off = (off + 3) & ~(size_t)3;      // 16B-align pack
  int4* pack   = (int4*)(W + off); off += (size_t)B_ * E_ * 4;
  int* rowptr  = (int*)(W + off); off += C_ + 1;
  int* qcnt    = (int*)(W + off); off += C_ * Q_;
  int* csr_e   = (int*)(W + off); off += E_;

  // merged setup: init (1024 blocks) | prep (144) | count (4000)
  k_setup<<<1024 + 144 + 4000, 256, 0, stream>>>(W_ih, W_hh, dst,
                                                 hnA, xnA, WBhi, WBlo, WihT2, qcnt);
  k_embfold<<<C_, 256, 0, stream>>>(emb, Wq, Wk, Wv, Wskip, WihT2, embW, gihemb);
  k_scan<<<1, 1024, 0, stream>>>(qcnt, rowptr);
  k_scatter<<<C_ * Q_ / 4, 256, 0, stream>>>(dst, rowptr, qcnt, csr_e);
  k_pack<<<B_ * E_ / 256, 256, 0, stream>>>(src, csr_e, ea0, pack);

  float* hn_final = (float*)d_out;
  float* xn_final = (float*)d_out + (size_t)N_ * HID;

  // t=0 producer
  k_node_pre<<<N_ / 4, 256, 0, stream>>>(X, y, embW, Wk, bk, Wv, bv,
                                         xnA, kA, vA, wiA, 0);

  for (int t = 0; t < HIST; ++t) {
    const bool last = (t == HIST - 1);
    const bool even = ((t & 1) == 0);
    k_node_main<<<N_ / 16, 256, 0, stream>>>(rowptr, pack, X, y, xnA, embW, gihemb,
                                             Wq, bq, Wskip, bskip, Wk, bk, Wv, bv, We, be,
                                             even ? kA : kB, even ? vA : vB, even ? wiA : wiB,
                                             even ? kB : kA, even ? vB : vA, even ? wiB : wiA,
                                             WBhi, WBlo,
                                             b_ih, b_hh, Wout, bout,
                                             hnA,
                                             last ? hn_final : hnA,
                                             last ? xn_final : xnA,
                                             t, last ? 1 : 0);
  }
}